// Round 11
// baseline (1315.052 us; speedup 1.0000x reference)
//
#include <hip/hip_runtime.h>
#include <hip/hip_fp16.h>

#define NB 8
#define NPTS 4096
#define NS 1024
#define NK 32
#define NM (NB*NS*NK)   // 262144 grouped points

typedef _Float16 f16x8 __attribute__((ext_vector_type(8)));
typedef float    f32x4 __attribute__((ext_vector_type(4)));
typedef float    f32x2 __attribute__((ext_vector_type(2)));

__device__ __forceinline__ float bf2f(unsigned short u){ return __uint_as_float(((unsigned)u)<<16); }
__device__ __forceinline__ unsigned short f2bf(float f){
  unsigned u = __float_as_uint(f);
  u = u + 0x7fffu + ((u>>16)&1u);   // RNE
  return (unsigned short)(u>>16);
}
__device__ __forceinline__ unsigned long long umax64(unsigned long long a, unsigned long long b){ return a>b?a:b; }
__device__ __forceinline__ unsigned long long umin64(unsigned long long a, unsigned long long b){ return a<b?a:b; }
__device__ __forceinline__ unsigned umin3u(unsigned a, unsigned b, unsigned c){
  unsigned m = a<b?a:b; return m<c?m:c;   // -> v_min3_u32
}

// ---- DPP wave64 reduce: row_shr 1/2/4/8 + row_bcast 15/31, result in lane 63.
#define DPP_STEP_MAX(x, ctrl, rm) { \
  unsigned _t = (unsigned)__builtin_amdgcn_update_dpp((int)(x), (int)(x), (ctrl), (rm), 0xf, false); \
  (x) = ((x) > _t) ? (x) : _t; }
#define DPP_STEP_MIN(x, ctrl, rm) { \
  unsigned _t = (unsigned)__builtin_amdgcn_update_dpp((int)(x), (int)(x), (ctrl), (rm), 0xf, false); \
  (x) = ((x) < _t) ? (x) : _t; }

__device__ __forceinline__ unsigned wave_max_u32(unsigned x){
  DPP_STEP_MAX(x, 0x111, 0xf);
  DPP_STEP_MAX(x, 0x112, 0xf);
  DPP_STEP_MAX(x, 0x114, 0xf);
  DPP_STEP_MAX(x, 0x118, 0xf);
  DPP_STEP_MAX(x, 0x142, 0xa);
  DPP_STEP_MAX(x, 0x143, 0xc);
  return (unsigned)__builtin_amdgcn_readlane((int)x, 63);
}
__device__ __forceinline__ unsigned wave_min_u32(unsigned x){
  DPP_STEP_MIN(x, 0x111, 0xf);
  DPP_STEP_MIN(x, 0x112, 0xf);
  DPP_STEP_MIN(x, 0x114, 0xf);
  DPP_STEP_MIN(x, 0x118, 0xf);
  DPP_STEP_MIN(x, 0x142, 0xa);
  DPP_STEP_MIN(x, 0x143, 0xc);
  return (unsigned)__builtin_amdgcn_readlane((int)x, 63);
}

// Runtime dtype detection (block-uniform scalar branch): f32 data read as bf16
// halves decodes huge/denormal or exact-zero; true bf16 N(0,1) does not.
__device__ __forceinline__ bool detect_f32(const unsigned short* __restrict__ u){
  int huge_=0, zero_=0;
  #pragma unroll
  for (int i=0;i<64;i++){
    unsigned short w = u[i];
    if ((w & 0x7fffu) == 0) { zero_++; continue; }
    float a = fabsf(bf2f(w));
    if (a > 1e6f || a < 1e-6f) huge_++;
  }
  return (huge_ >= 8) || (zero_ >= 24);
}
__device__ __forceinline__ float ldin(const void* p, size_t i, bool f32){
  if (f32) return ((const float*)p)[i];
  else     return bf2f(((const unsigned short*)p)[i]);
}

// ---------------------------------------------------------------------------
// FPS (round-10 structure, 531 us measured, split into 8 dispatches of 128
// iters for top-5 visibility: with fps rows at ~70 us, any hidden >=75 us
// kernel surfaces in the profile). State across dispatches: per-thread
// dist[8] f32x2 (exact f32 in ws, aliases knn buffer region which is written
// only after fps completes) + far scalar. it0==0 initializes, so the 0xAA
// re-poison per launch is harmless. Index decisions bit-identical.
// ---------------------------------------------------------------------------
__global__ __launch_bounds__(256) void fps_kernel(const void* __restrict__ pc1,
                                                  int* __restrict__ fps_out,
                                                  float4* __restrict__ dws,
                                                  int* __restrict__ farws,
                                                  int it0){
  __shared__ __align__(16) float4 cp4[NPTS];
  __shared__ __align__(16) unsigned long long part[2][4];
  int b = blockIdx.x, t = threadIdx.x;
  const bool f32 = detect_f32((const unsigned short*)pc1);
  const size_t base = (size_t)b*3*NPTS;
  for (int i=t;i<NPTS;i+=256){
    float4 v;
    v.x = ldin(pc1, base+i, f32);
    v.y = ldin(pc1, base+NPTS+i, f32);
    v.z = ldin(pc1, base+2*NPTS+i, f32);
    v.w = 0.f;
    cp4[i] = v;
  }
  __syncthreads();
  f32x2 px[8],py[8],pz[8],dist[8];
  #pragma unroll
  for (int j=0;j<8;j++){
    float4 a = cp4[t*16+2*j], c = cp4[t*16+2*j+1];
    px[j] = f32x2{a.x, c.x};
    py[j] = f32x2{a.y, c.y};
    pz[j] = f32x2{a.z, c.z};
  }
  int far;
  float4* dp = dws + ((size_t)b*256 + t)*4;
  if (it0 == 0){
    #pragma unroll
    for (int j=0;j<8;j++) dist[j] = f32x2{1e10f, 1e10f};
    far = 0;
  } else {
    #pragma unroll
    for (int j=0;j<4;j++){
      float4 d = dp[j];
      dist[2*j]   = f32x2{d.x, d.y};
      dist[2*j+1] = f32x2{d.z, d.w};
    }
    far = farws[b];
  }
  int w = t>>6, lane = t&63;
  for (int it=it0; it<it0+128; it++){
    if (t==0) fps_out[b*NS+it] = far;
    float4 cc = cp4[far];
    f32x2 vcx = f32x2{cc.x,cc.x}, vcy = f32x2{cc.y,cc.y}, vcz = f32x2{cc.z,cc.z};
    {
      #pragma clang fp contract(off)
      #pragma unroll
      for (int j=0;j<8;j++){
        f32x2 dx = px[j]-vcx, dy = py[j]-vcy, dz = pz[j]-vcz;
        f32x2 d  = (dx*dx + dy*dy) + dz*dz;     // exact RN order: ((x2+y2)+z2)
        dist[j]  = __builtin_elementwise_min(dist[j], d);
      }
    }
    float d_[16];
    #pragma unroll
    for (int j=0;j<8;j++){ d_[2*j]=dist[j][0]; d_[2*j+1]=dist[j][1]; }
    float a0 = fmaxf(fmaxf(d_[0],d_[1]),d_[2]);      // -> v_max3_f32
    float a1 = fmaxf(fmaxf(d_[3],d_[4]),d_[5]);
    float a2 = fmaxf(fmaxf(d_[6],d_[7]),d_[8]);
    float a3 = fmaxf(fmaxf(d_[9],d_[10]),d_[11]);
    float a4 = fmaxf(fmaxf(d_[12],d_[13]),d_[14]);
    float b0 = fmaxf(fmaxf(a0,a1),a2);
    float b1 = fmaxf(fmaxf(a3,a4),d_[15]);
    float bl = fmaxf(b0,b1);
    int li = 0;
    #pragma unroll
    for (int i=15;i>=0;i--) if (d_[i]==bl) li = i;   // descending: final = lowest i
    unsigned blu = __float_as_uint(bl);               // dist>=0: bits monotone
    unsigned wm = wave_max_u32(blu);
    unsigned long long mk = __ballot(blu == wm);
    int l = __builtin_ctzll(mk);                      // lowest lane = lowest n
    int idx = __builtin_amdgcn_readlane(t*16+li, l);
    if (lane==0) part[it&1][w] = ((unsigned long long)wm<<32) | (unsigned)(NPTS-1-idx);
    __syncthreads();
    const ulonglong2* pp = (const ulonglong2*)&part[it&1][0];
    ulonglong2 A = pp[0], B = pp[1];
    unsigned long long m = umax64(umax64(A.x,A.y), umax64(B.x,B.y));
    far = NPTS-1 - (int)(m & 0xffffffffu);
  }
  #pragma unroll
  for (int j=0;j<4;j++)
    dp[j] = make_float4(dist[2*j][0], dist[2*j][1], dist[2*j+1][0], dist[2*j+1][1]);
  if (t==0) farws[b] = far;
}

// ---------------------------------------------------------------------------
// kNN v3 (unchanged): no xyz LDS; dists computed during coalesced staging
// into padded dbs; barrier-free per-wave top-32 + exact rank-merge.
// ---------------------------------------------------------------------------
__global__ __launch_bounds__(256) void knn_kernel(const void* __restrict__ pc1,
                                                  const int* __restrict__ fps_idx,
                                                  float* __restrict__ new_xyz,
                                                  int* __restrict__ knn_idx){
  __shared__ __align__(16) unsigned dbs[256*20];                 // 20 KB
  __shared__ __align__(16) unsigned long long lists[4][NK];      // 1 KB
  int blk = blockIdx.x;   // b*1024 + s
  int b = blk >> 10;
  int t = threadIdx.x;
  int w = t>>6, lane = t&63;
  const bool f32 = detect_f32((const unsigned short*)pc1);
  const size_t base = (size_t)b*3*NPTS;
  int n0 = fps_idx[blk];
  float qx = ldin(pc1, base+n0, f32);
  float qy = ldin(pc1, base+NPTS+n0, f32);
  float qz = ldin(pc1, base+2*NPTS+n0, f32);
  if (t==0){ new_xyz[(size_t)blk*3]=qx; new_xyz[(size_t)blk*3+1]=qy; new_xyz[(size_t)blk*3+2]=qz; }
  float qn = __fadd_rn(__fadd_rn(__fmul_rn(qx,qx),__fmul_rn(qy,qy)),__fmul_rn(qz,qz));
  #pragma unroll
  for (int k=0;k<16;k++){
    int n = t + 256*k;                               // coalesced global reads
    float x = ldin(pc1, base+n, f32);
    float y = ldin(pc1, base+NPTS+n, f32);
    float z = ldin(pc1, base+2*NPTS+n, f32);
    float pn = __fadd_rn(__fadd_rn(__fmul_rn(x,x),__fmul_rn(y,y)),__fmul_rn(z,z));
    float dt = __fadd_rn(__fadd_rn(__fmul_rn(qx,x),__fmul_rn(qy,y)),__fmul_rn(qz,z));
    float d  = __fsub_rn(__fadd_rn(qn,pn), __fmul_rn(2.f,dt));
    unsigned u = __float_as_uint(d);
    u = (u & 0x80000000u) ? ~u : (u | 0x80000000u);  // order-preserving map
    dbs[(n>>4)*20 + (n&15)] = u;                     // transpose to owner layout
  }
  __syncthreads();
  unsigned gm[4]; int gj[4];
  #pragma unroll
  for (int g=0; g<4; g++){
    uint4 v = *(const uint4*)&dbs[t*20 + 4*g];
    unsigned m = v.x; int j = 0;
    if (v.y < m){ m = v.y; j = 1; }                  // strict <, ascending: first min
    if (v.z < m){ m = v.z; j = 2; }
    if (v.w < m){ m = v.w; j = 3; }
    gm[g] = m; gj[g] = j;
  }
  #pragma unroll 1
  for (int r=0; r<NK; r++){
    unsigned bl = umin3u(gm[0],gm[1],gm[2]);
    bl = bl < gm[3] ? bl : gm[3];
    int bg = 3;                                      // descending: final = lowest g
    if (gm[2]==bl) bg=2;
    if (gm[1]==bl) bg=1;
    if (gm[0]==bl) bg=0;
    int lj = gj[0];
    if (bg==1) lj=gj[1];
    if (bg==2) lj=gj[2];
    if (bg==3) lj=gj[3];
    int bn = (t<<4) + (bg<<2) + lj;                  // global point idx
    uint4 gv = *(const uint4*)&dbs[t*20 + (bg<<2)];  // speculative reload
    unsigned wm = wave_min_u32(bl);
    unsigned long long mk = __ballot(bl == wm);
    int l = __builtin_ctzll(mk);                     // lowest lane = lowest idx on tie
    int idx = __builtin_amdgcn_readlane(bn, l);
    if (lane==0) lists[w][r] = ((unsigned long long)wm<<32) | (unsigned)idx;
    if (lane==l){
      unsigned g0 = (lj==0)?0xFFFFFFFFu:gv.x;
      unsigned g1 = (lj==1)?0xFFFFFFFFu:gv.y;
      unsigned g2 = (lj==2)?0xFFFFFFFFu:gv.z;
      unsigned g3 = (lj==3)?0xFFFFFFFFu:gv.w;
      uint4 nv; nv.x=g0; nv.y=g1; nv.z=g2; nv.w=g3;
      *(uint4*)&dbs[t*20 + (bg<<2)] = nv;
      unsigned m = g0; int j = 0;
      if (g1 < m){ m=g1; j=1; }
      if (g2 < m){ m=g2; j=2; }
      if (g3 < m){ m=g3; j=3; }
      if (bg==0){ gm[0]=m; gj[0]=j; }
      if (bg==1){ gm[1]=m; gj[1]=j; }
      if (bg==2){ gm[2]=m; gj[2]=j; }
      if (bg==3){ gm[3]=m; gj[3]=j; }
    }
  }
  __syncthreads();
  if (t < 128){
    int cl = t>>5, p = t&31;
    unsigned long long K = lists[cl][p];
    int rank = p;                                    // lists strictly increasing
    #pragma unroll
    for (int ol=0; ol<4; ol++){
      if (ol==cl) continue;
      int lo = 0;                                    // count of elems < K
      if (lists[ol][15]    < K) lo  = 16;
      if (lists[ol][lo+7]  < K) lo += 8;
      if (lists[ol][lo+3]  < K) lo += 4;
      if (lists[ol][lo+1]  < K) lo += 2;
      if (lists[ol][lo]    < K) lo += 1;
      rank += lo;
    }
    if (rank < NK) knn_idx[(size_t)blk*NK + rank] = (int)(K & 0xffffffffu);
  }
}

// ---------------------------------------------------------------------------
// feats [B,128,N] (f32/bf16) -> G [B,N,136] fp16; block 0 also zeroes the six
// stat buffers (6144 f32) so no memset nodes are needed (ws is 0xAA-poisoned).
// ---------------------------------------------------------------------------
__global__ __launch_bounds__(256) void feat_transpose(const void* __restrict__ feats,
                                                      const void* __restrict__ pc1,
                                                      _Float16* __restrict__ G,
                                                      float* __restrict__ statz){
  __shared__ float tile[128][65];
  const bool f32 = detect_f32((const unsigned short*)pc1);
  int blk = blockIdx.x;             // b*64 + ntile
  int b = blk>>6, n0 = (blk&63)*64;
  int t = threadIdx.x;
  if (blk==0){
    for (int i=t;i<6144;i+=256) statz[i]=0.f;
  }
  #pragma unroll 4
  for (int i=0;i<32;i++){
    int idx = i*256 + t;
    int c = idx>>6, n = idx&63;
    tile[c][n] = ldin(feats, ((size_t)b*128 + c)*NPTS + n0 + n, f32);
  }
  __syncthreads();
  #pragma unroll 4
  for (int i=0;i<32;i++){
    int idx = i*256 + t;
    int n = idx>>7, c = idx&127;
    G[((size_t)b*NPTS + n0 + n)*136 + 3 + c] = (_Float16)tile[c][n];
  }
  if (t<64){
    size_t gb = ((size_t)b*NPTS + n0 + t)*136;
    G[gb]=(_Float16)0.f; G[gb+1]=(_Float16)0.f; G[gb+2]=(_Float16)0.f;
    #pragma unroll
    for (int c=131;c<136;c++) G[gb+c]=(_Float16)0.f;
  }
}

// ---------------------------------------------------------------------------
// MFMA conv: block = 128 pts x 128 outs, 4 waves at 64x64, K chunks of 32.
// mfma_f32_16x16x32_f16, f32 accumulate. LAYER 1: A from G (knn gather)+dxyz,
// K 131->160. LAYER 2/3: mu/rs computed inline from prev-layer sums, then
// A = relu((Hin-mu)*rs). Stats -> per-(b,o) f32 atomics. Biases cancel.
// ---------------------------------------------------------------------------
template<int LAYER>
__global__ __launch_bounds__(256) void conv_mfma(
    const void* __restrict__ pc1,
    const _Float16* __restrict__ G,
    const int* __restrict__ knn_idx,
    const float* __restrict__ new_xyz,
    const _Float16* __restrict__ Hin,
    const float* __restrict__ gp1,
    const float* __restrict__ gp2,
    const void* __restrict__ W,
    _Float16* __restrict__ Hout,
    float* __restrict__ gs1, float* __restrict__ gs2)
{
  constexpr int KC  = (LAYER==1)?131:128;
  constexpr int KCP = (LAYER==1)?160:128;
  constexpr int HSW = (LAYER==1)?168:136;
  __shared__ __align__(16) _Float16 hs[128][HSW];
  __shared__ __align__(16) _Float16 wt[128][40];
  __shared__ float red1[4][64], red2[4][64];
  __shared__ int   nidx[128];
  __shared__ float cxyz[4][3];
  __shared__ float smu[128], srs[128];
  int blk = blockIdx.x;
  int m0 = blk*128;
  int b  = m0 >> 15;
  int t  = threadIdx.x;
  const bool f32 = detect_f32((const unsigned short*)pc1);
  int w = t>>6, lane = t&63;
  int l16 = lane&15, q = lane>>4, q8 = q*8;
  int wr = (w&1)*64, wc = (w>>1)*64;

  if (LAYER==1){
    if (t<128) nidx[t] = knn_idx[m0+t];
    if (t<12)  cxyz[t/3][t%3] = new_xyz[(size_t)(m0>>5)*3 + t];
    __syncthreads();
    for (int u=t; u<128*17; u+=256){
      int p = u/17, qq = u - p*17;
      const f16x8* src = (const f16x8*)(G + ((size_t)b*NPTS + nidx[p])*136 + qq*8);
      *(f16x8*)&hs[p][qq*8] = *src;
    }
    for (int u=t; u<128*3; u+=256){
      int p = u/3, qq = u - p*3;
      uint4 z; z.x=z.y=z.z=z.w=0u;
      *(uint4*)&hs[p][136+qq*8] = z;
    }
    __syncthreads();
    if (t<128){
      int n = nidx[t];
      float cx = cxyz[t>>5][0], cy = cxyz[t>>5][1], cz = cxyz[t>>5][2];
      hs[t][0] = (_Float16)(ldin(pc1, ((size_t)b*3+0)*NPTS+n, f32) - cx);
      hs[t][1] = (_Float16)(ldin(pc1, ((size_t)b*3+1)*NPTS+n, f32) - cy);
      hs[t][2] = (_Float16)(ldin(pc1, ((size_t)b*3+2)*NPTS+n, f32) - cz);
    }
    __syncthreads();
  } else {
    if (t<128){
      const float inv = 1.0f/32768.0f;
      float m = gp1[b*128+t]*inv;
      smu[t] = m;
      srs[t] = rsqrtf(gp2[b*128+t]*inv - m*m + 1e-5f);
    }
    __syncthreads();
    int p = t & 127, hi = t>>7;
    const _Float16* src = Hin + (size_t)(m0+p)*128 + hi*64;
    #pragma unroll
    for (int j=0;j<8;j++){
      f16x8 v = *(const f16x8*)(src + j*8);
      f16x8 o;
      #pragma unroll
      for (int e=0;e<8;e++){
        int c = hi*64 + j*8 + e;
        float x = ((float)v[e] - smu[c]) * srs[c];
        o[e] = (_Float16)(x > 0.f ? x : 0.f);
      }
      *(f16x8*)&hs[p][hi*64 + j*8] = o;
    }
    __syncthreads();
  }

  f32x4 acc[4][4];
  #pragma unroll
  for (int i=0;i<4;i++)
    #pragma unroll
    for (int c=0;c<4;c++){ acc[i][c][0]=0.f; acc[i][c][1]=0.f; acc[i][c][2]=0.f; acc[i][c][3]=0.f; }

  for (int k0=0; k0<KCP; k0+=32){
    {
      int o = t>>1, half = t&1;
      f16x8 w0, w1;
      #pragma unroll
      for (int jj=0;jj<8;jj++){
        int c0 = k0 + half*16 + jj, c1 = c0 + 8;
        w0[jj] = (_Float16)((c0<KC) ? ldin(W, (size_t)o*KC + c0, f32) : 0.f);
        w1[jj] = (_Float16)((c1<KC) ? ldin(W, (size_t)o*KC + c1, f32) : 0.f);
      }
      *(f16x8*)&wt[o][half*16]     = w0;
      *(f16x8*)&wt[o][half*16 + 8] = w1;
    }
    __syncthreads();
    f16x8 av[4], bv[4];
    #pragma unroll
    for (int i=0;i<4;i++) av[i] = *(const f16x8*)&hs[wr + i*16 + l16][k0 + q8];
    #pragma unroll
    for (int c=0;c<4;c++) bv[c] = *(const f16x8*)&wt[wc + c*16 + l16][q8];
    #pragma unroll
    for (int i=0;i<4;i++)
      #pragma unroll
      for (int c=0;c<4;c++)
        acc[i][c] = __builtin_amdgcn_mfma_f32_16x16x32_f16(av[i], bv[c], acc[i][c], 0,0,0);
    __syncthreads();
  }

  #pragma unroll
  for (int c=0;c<4;c++){
    int o = wc + c*16 + l16;
    float s1=0.f, s2=0.f;
    #pragma unroll
    for (int i=0;i<4;i++){
      int row = wr + i*16 + q*4;
      #pragma unroll
      for (int r=0;r<4;r++){
        float v = acc[i][c][r];
        Hout[(size_t)(m0 + row + r)*128 + o] = (_Float16)v;
        s1 += v; s2 = fmaf(v,v,s2);
      }
    }
    s1 += __shfl_xor(s1, 16, 64); s1 += __shfl_xor(s1, 32, 64);
    s2 += __shfl_xor(s2, 16, 64); s2 += __shfl_xor(s2, 32, 64);
    if (q==0){ red1[w][c*16+l16] = s1; red2[w][c*16+l16] = s2; }
  }
  __syncthreads();
  if (t<128){
    int lo = t & 63, g = (t>>6)*2;
    unsafeAtomicAdd(&gs1[b*128+t], red1[g][lo] + red1[g+1][lo]);
    unsafeAtomicAdd(&gs2[b*128+t], red2[g][lo] + red2[g+1][lo]);
  }
}

// ---------------------------------------------------------------------------
// Final: per (b,s): mu/rs from layer-3 sums, norm+relu, max over K, fc 128->3
// ---------------------------------------------------------------------------
__global__ __launch_bounds__(128) void final_kernel(
    const void* __restrict__ pc1,
    const _Float16* __restrict__ H,
    const float* __restrict__ gp1, const float* __restrict__ gp2,
    const void* __restrict__ fc_w, const void* __restrict__ fc_b,
    void* __restrict__ outv)
{
  int blk = blockIdx.x;       // b*1024+s
  int b = blk>>10, s = blk & 1023;
  int o = threadIdx.x;
  const bool f32 = detect_f32((const unsigned short*)pc1);
  int bo = b*128 + o;
  const float inv = 1.0f/32768.0f;
  float mu_ = gp1[bo]*inv;
  float rs_ = rsqrtf(gp2[bo]*inv - mu_*mu_ + 1e-5f);
  const _Float16* hp = H + (size_t)blk*NK*128 + o;
  float m = -1e30f;
  #pragma unroll 4
  for(int k=0;k<NK;k++){
    float v = ((float)hp[(size_t)k*128] - mu_)*rs_;
    m = fmaxf(m, v);
  }
  m = fmaxf(m, 0.f);
  __shared__ float mv[128];
  mv[o] = m;
  __syncthreads();
  if (o<3){
    float acc = ldin(fc_b, o, f32);
    for(int c=0;c<128;c++) acc = fmaf(ldin(fc_w, (size_t)o*128+c, f32), mv[c], acc);
    size_t oi = ((size_t)b*3 + o)*NS + s;
    if (f32) ((float*)outv)[oi] = acc;
    else     ((unsigned short*)outv)[oi] = f2bf(acc);
  }
}

// ---------------------------------------------------------------------------
extern "C" void kernel_launch(void* const* d_in, const int* in_sizes, int n_in,
                              void* d_out, int out_size, void* d_ws, size_t ws_size,
                              hipStream_t stream){
  const void* pc1   = d_in[0];
  const void* feats = d_in[1];
  const void* W1    = d_in[2];
  const void* W2    = d_in[4];
  const void* W3    = d_in[6];
  const void* fcw   = d_in[8];
  const void* fcb   = d_in[9];
  char* ws = (char*)d_ws;
  int*      fps  = (int*)     (ws + 0);          // 32768 B
  float*    nxyz = (float*)   (ws + 32768);      // 98304 B
  int*      knn  = (int*)     (ws + 131072);     // 1048576 B
  float*    st   = (float*)   (ws + 1179648);    // 6*1024*4 = 24576 B  [s1a s2a s1b s2b s1c s2c]
  _Float16* Ha   = (_Float16*)(ws + 1204224);    // 67108864 B
  _Float16* Hb   = (_Float16*)(ws + 68313088);   // 67108864 B (total 135421952)
  _Float16* G    = Hb;  // G (8.9 MB) aliases Hb: read only by conv1, Hb first written by conv2
  // fps inter-dispatch state aliases the knn region (knn_kernel writes it
  // only AFTER all fps dispatches): dist 256 KB + farws 32 B.
  float4*   dws  = (float4*)  (ws + 131072);
  int*      farws= (int*)     (ws + 131072 + 262144);

  feat_transpose<<<NB*64, 256, 0, stream>>>(feats, pc1, G, st);
  for (int it0 = 0; it0 < NS; it0 += 128)
    fps_kernel<<<NB, 256, 0, stream>>>(pc1, fps, dws, farws, it0);
  knn_kernel<<<NB*NS, 256, 0, stream>>>(pc1, fps, nxyz, knn);

  conv_mfma<1><<<NM/128, 256, 0, stream>>>(pc1, G, knn, nxyz,
      (const _Float16*)nullptr, (const float*)nullptr, (const float*)nullptr,
      W1, Ha, st, st+1024);
  conv_mfma<2><<<NM/128, 256, 0, stream>>>(pc1, G, knn, nxyz,
      Ha, st, st+1024, W2, Hb, st+2048, st+3072);
  conv_mfma<3><<<NM/128, 256, 0, stream>>>(pc1, G, knn, nxyz,
      Hb, st+2048, st+3072, W3, Ha, st+4096, st+5120);

  final_kernel<<<NB*NS, 128, 0, stream>>>(pc1, Ha, st+4096, st+5120, fcw, fcb, d_out);
}

// Round 12
// 1207.189 us; speedup vs baseline: 1.0894x; 1.0894x over previous
//
#include <hip/hip_runtime.h>
#include <hip/hip_fp16.h>

#define NB 8
#define NPTS 4096
#define NS 1024
#define NK 32
#define NM (NB*NS*NK)   // 262144 grouped points

typedef _Float16 f16x8 __attribute__((ext_vector_type(8)));
typedef float    f32x4 __attribute__((ext_vector_type(4)));
typedef float    f32x2 __attribute__((ext_vector_type(2)));

__device__ __forceinline__ float bf2f(unsigned short u){ return __uint_as_float(((unsigned)u)<<16); }
__device__ __forceinline__ unsigned short f2bf(float f){
  unsigned u = __float_as_uint(f);
  u = u + 0x7fffu + ((u>>16)&1u);   // RNE
  return (unsigned short)(u>>16);
}
__device__ __forceinline__ unsigned long long umax64(unsigned long long a, unsigned long long b){ return a>b?a:b; }
__device__ __forceinline__ unsigned long long umin64(unsigned long long a, unsigned long long b){ return a<b?a:b; }
__device__ __forceinline__ unsigned umin3u(unsigned a, unsigned b, unsigned c){
  unsigned m = a<b?a:b; return m<c?m:c;   // -> v_min3_u32
}

// ---- DPP wave64 reduce: row_shr 1/2/4/8 + row_bcast 15/31, result in lane 63.
#define DPP_STEP_MAX(x, ctrl, rm) { \
  unsigned _t = (unsigned)__builtin_amdgcn_update_dpp((int)(x), (int)(x), (ctrl), (rm), 0xf, false); \
  (x) = ((x) > _t) ? (x) : _t; }
#define DPP_STEP_MIN(x, ctrl, rm) { \
  unsigned _t = (unsigned)__builtin_amdgcn_update_dpp((int)(x), (int)(x), (ctrl), (rm), 0xf, false); \
  (x) = ((x) < _t) ? (x) : _t; }

__device__ __forceinline__ unsigned wave_max_u32(unsigned x){
  DPP_STEP_MAX(x, 0x111, 0xf);
  DPP_STEP_MAX(x, 0x112, 0xf);
  DPP_STEP_MAX(x, 0x114, 0xf);
  DPP_STEP_MAX(x, 0x118, 0xf);
  DPP_STEP_MAX(x, 0x142, 0xa);
  DPP_STEP_MAX(x, 0x143, 0xc);
  return (unsigned)__builtin_amdgcn_readlane((int)x, 63);
}
__device__ __forceinline__ unsigned wave_min_u32(unsigned x){
  DPP_STEP_MIN(x, 0x111, 0xf);
  DPP_STEP_MIN(x, 0x112, 0xf);
  DPP_STEP_MIN(x, 0x114, 0xf);
  DPP_STEP_MIN(x, 0x118, 0xf);
  DPP_STEP_MIN(x, 0x142, 0xa);
  DPP_STEP_MIN(x, 0x143, 0xc);
  return (unsigned)__builtin_amdgcn_readlane((int)x, 63);
}

// Runtime dtype detection (block-uniform scalar branch): f32 data read as bf16
// halves decodes huge/denormal or exact-zero; true bf16 N(0,1) does not.
__device__ __forceinline__ bool detect_f32(const unsigned short* __restrict__ u){
  int huge_=0, zero_=0;
  #pragma unroll
  for (int i=0;i<64;i++){
    unsigned short w = u[i];
    if ((w & 0x7fffu) == 0) { zero_++; continue; }
    float a = fabsf(bf2f(w));
    if (a > 1e6f || a < 1e-6f) huge_++;
  }
  return (huge_ >= 8) || (zero_ >= 24);
}
__device__ __forceinline__ float ldin(const void* p, size_t i, bool f32){
  if (f32) return ((const float*)p)[i];
  else     return bf2f(((const unsigned short*)p)[i]);
}

// ---------------------------------------------------------------------------
// FPS (round-10 verbatim, measured 531 us): one block/batch, 256 thr, 16
// contiguous pts/thread as 8 f32x2 packed pairs in regs + cp4 in LDS. The
// 66KB LDS caps occupancy at 1 block/CU, which lets the allocator keep the
// arrays register-resident (VGPR 88). Register-only variants (r7-9) were
// 2.5x slower even with VGPRs granted; the 8-way split (r11) costs +133 us.
// ---------------------------------------------------------------------------
__global__ __launch_bounds__(256) void fps_kernel(const void* __restrict__ pc1,
                                                  int* __restrict__ fps_out){
  __shared__ __align__(16) float4 cp4[NPTS];
  __shared__ __align__(16) unsigned long long part[2][4];
  int b = blockIdx.x, t = threadIdx.x;
  const bool f32 = detect_f32((const unsigned short*)pc1);
  const size_t base = (size_t)b*3*NPTS;
  for (int i=t;i<NPTS;i+=256){
    float4 v;
    v.x = ldin(pc1, base+i, f32);
    v.y = ldin(pc1, base+NPTS+i, f32);
    v.z = ldin(pc1, base+2*NPTS+i, f32);
    v.w = 0.f;
    cp4[i] = v;
  }
  __syncthreads();
  f32x2 px[8],py[8],pz[8],dist[8];
  #pragma unroll
  for (int j=0;j<8;j++){
    float4 a = cp4[t*16+2*j], c = cp4[t*16+2*j+1];
    px[j] = f32x2{a.x, c.x};
    py[j] = f32x2{a.y, c.y};
    pz[j] = f32x2{a.z, c.z};
    dist[j] = f32x2{1e10f, 1e10f};
  }
  int far = 0;
  int w = t>>6, lane = t&63;
  for (int it=0; it<NS; it++){
    if (t==0) fps_out[b*NS+it] = far;
    float4 cc = cp4[far];
    f32x2 vcx = f32x2{cc.x,cc.x}, vcy = f32x2{cc.y,cc.y}, vcz = f32x2{cc.z,cc.z};
    {
      #pragma clang fp contract(off)
      #pragma unroll
      for (int j=0;j<8;j++){
        f32x2 dx = px[j]-vcx, dy = py[j]-vcy, dz = pz[j]-vcz;
        f32x2 d  = (dx*dx + dy*dy) + dz*dz;     // exact RN order: ((x2+y2)+z2)
        dist[j]  = __builtin_elementwise_min(dist[j], d);
      }
    }
    float d_[16];
    #pragma unroll
    for (int j=0;j<8;j++){ d_[2*j]=dist[j][0]; d_[2*j+1]=dist[j][1]; }
    float a0 = fmaxf(fmaxf(d_[0],d_[1]),d_[2]);      // -> v_max3_f32
    float a1 = fmaxf(fmaxf(d_[3],d_[4]),d_[5]);
    float a2 = fmaxf(fmaxf(d_[6],d_[7]),d_[8]);
    float a3 = fmaxf(fmaxf(d_[9],d_[10]),d_[11]);
    float a4 = fmaxf(fmaxf(d_[12],d_[13]),d_[14]);
    float b0 = fmaxf(fmaxf(a0,a1),a2);
    float b1 = fmaxf(fmaxf(a3,a4),d_[15]);
    float bl = fmaxf(b0,b1);
    int li = 0;
    #pragma unroll
    for (int i=15;i>=0;i--) if (d_[i]==bl) li = i;   // descending: final = lowest i
    unsigned blu = __float_as_uint(bl);               // dist>=0: bits monotone
    unsigned wm = wave_max_u32(blu);
    unsigned long long mk = __ballot(blu == wm);
    int l = __builtin_ctzll(mk);                      // lowest lane = lowest n
    int idx = __builtin_amdgcn_readlane(t*16+li, l);
    if (lane==0) part[it&1][w] = ((unsigned long long)wm<<32) | (unsigned)(NPTS-1-idx);
    __syncthreads();
    const ulonglong2* pp = (const ulonglong2*)&part[it&1][0];
    ulonglong2 A = pp[0], B = pp[1];
    unsigned long long m = umax64(umax64(A.x,A.y), umax64(B.x,B.y));
    far = NPTS-1 - (int)(m & 0xffffffffu);
  }
}

// ---------------------------------------------------------------------------
// kNN v4: one block per (b,s), 256 thr. dv[16] entirely in REGISTERS (r11
// profile: v3's dbs LDS cost 8.09M bank-conflict cycles + 101% VALUBusy).
// Per wave, 32 barrier-free rounds: min3 tree over 16 regs + descending
// first-match scan (lowest local idx on tie) + DPP min + ballot/ctz (lowest
// lane = lowest n) + predicated kill of the winner's reg. Then 1 barrier +
// exact rank-merge of the 4 sorted unique (dist,idx) lists via binary search.
// Set and order match lax.top_k(-d) exactly. LDS = 1KB; ~35 live VGPRs
// (dist math per float4-chunk so coord temps die early — no spill, r7 lesson).
// ---------------------------------------------------------------------------
__global__ __launch_bounds__(256) void knn_kernel(const void* __restrict__ pc1,
                                                  const int* __restrict__ fps_idx,
                                                  float* __restrict__ new_xyz,
                                                  int* __restrict__ knn_idx){
  __shared__ __align__(16) unsigned long long lists[4][NK];      // 1 KB
  int blk = blockIdx.x;   // b*1024 + s
  int b = blk >> 10;
  int t = threadIdx.x;
  int w = t>>6, lane = t&63;
  const bool f32 = detect_f32((const unsigned short*)pc1);
  const size_t base = (size_t)b*3*NPTS;
  int n0 = fps_idx[blk];
  float qx = ldin(pc1, base+n0, f32);
  float qy = ldin(pc1, base+NPTS+n0, f32);
  float qz = ldin(pc1, base+2*NPTS+n0, f32);
  if (t==0){ new_xyz[(size_t)blk*3]=qx; new_xyz[(size_t)blk*3+1]=qy; new_xyz[(size_t)blk*3+2]=qz; }
  float qn = __fadd_rn(__fadd_rn(__fmul_rn(qx,qx),__fmul_rn(qy,qy)),__fmul_rn(qz,qz));
  unsigned dv[16];
  if (f32){
    const float* fp = (const float*)pc1;
    const float4* bx = (const float4*)(fp + base)          + t*4;
    const float4* by = (const float4*)(fp + base + NPTS)   + t*4;
    const float4* bz = (const float4*)(fp + base + 2*NPTS) + t*4;
    #pragma unroll
    for (int j=0;j<4;j++){
      float4 vx = bx[j], vy = by[j], vz = bz[j];
      #pragma unroll
      for (int e=0;e<4;e++){
        float x = (&vx.x)[e], y = (&vy.x)[e], z = (&vz.x)[e];
        float pn = __fadd_rn(__fadd_rn(__fmul_rn(x,x),__fmul_rn(y,y)),__fmul_rn(z,z));
        float dt = __fadd_rn(__fadd_rn(__fmul_rn(qx,x),__fmul_rn(qy,y)),__fmul_rn(qz,z));
        float d  = __fsub_rn(__fadd_rn(qn,pn), __fmul_rn(2.f,dt));
        unsigned u = __float_as_uint(d);
        dv[4*j+e] = (u & 0x80000000u) ? ~u : (u | 0x80000000u);  // order-preserving
      }
    }
  } else {
    #pragma unroll
    for (int i=0;i<16;i++){
      int n = t*16 + i;
      float x = ldin(pc1, base+n, f32);
      float y = ldin(pc1, base+NPTS+n, f32);
      float z = ldin(pc1, base+2*NPTS+n, f32);
      float pn = __fadd_rn(__fadd_rn(__fmul_rn(x,x),__fmul_rn(y,y)),__fmul_rn(z,z));
      float dt = __fadd_rn(__fadd_rn(__fmul_rn(qx,x),__fmul_rn(qy,y)),__fmul_rn(qz,z));
      float d  = __fsub_rn(__fadd_rn(qn,pn), __fmul_rn(2.f,dt));
      unsigned u = __float_as_uint(d);
      dv[i] = (u & 0x80000000u) ? ~u : (u | 0x80000000u);
    }
  }
  #pragma unroll 1
  for (int r=0; r<NK; r++){
    unsigned a0 = umin3u(dv[0],dv[1],dv[2]);
    unsigned a1 = umin3u(dv[3],dv[4],dv[5]);
    unsigned a2 = umin3u(dv[6],dv[7],dv[8]);
    unsigned a3 = umin3u(dv[9],dv[10],dv[11]);
    unsigned a4 = umin3u(dv[12],dv[13],dv[14]);
    unsigned b0 = umin3u(a0,a1,a2);
    unsigned b1 = umin3u(a3,a4,dv[15]);
    unsigned bl = b0<b1 ? b0 : b1;
    int li = 0;
    #pragma unroll
    for (int i=15;i>=0;i--) if (dv[i]==bl) li = i;    // descending: lowest i wins
    unsigned wm = wave_min_u32(bl);
    unsigned long long mk = __ballot(bl == wm);
    int l = __builtin_ctzll(mk);                      // lowest lane = lowest n on tie
    int idx = __builtin_amdgcn_readlane(t*16 + li, l);
    if (lane==0) lists[w][r] = ((unsigned long long)wm<<32) | (unsigned)idx;
    bool win = (lane == l);
    #pragma unroll
    for (int i=0;i<16;i++)
      if (win && (li==i)) dv[i] = 0xFFFFFFFFu;        // cndmask, no scratch
  }
  __syncthreads();
  if (t < 128){
    int cl = t>>5, p = t&31;
    unsigned long long K = lists[cl][p];
    int rank = p;                                     // lists strictly increasing
    #pragma unroll
    for (int ol=0; ol<4; ol++){
      if (ol==cl) continue;
      int lo = 0;                                     // count of elems < K
      if (lists[ol][15]    < K) lo  = 16;
      if (lists[ol][lo+7]  < K) lo += 8;
      if (lists[ol][lo+3]  < K) lo += 4;
      if (lists[ol][lo+1]  < K) lo += 2;
      if (lists[ol][lo]    < K) lo += 1;
      rank += lo;
    }
    if (rank < NK) knn_idx[(size_t)blk*NK + rank] = (int)(K & 0xffffffffu);
  }
}

// ---------------------------------------------------------------------------
// feats [B,128,N] (f32/bf16) -> G [B,N,136] fp16; block 0 also zeroes the six
// stat buffers (6144 f32) so no memset nodes are needed (ws is 0xAA-poisoned).
// ---------------------------------------------------------------------------
__global__ __launch_bounds__(256) void feat_transpose(const void* __restrict__ feats,
                                                      const void* __restrict__ pc1,
                                                      _Float16* __restrict__ G,
                                                      float* __restrict__ statz){
  __shared__ float tile[128][65];
  const bool f32 = detect_f32((const unsigned short*)pc1);
  int blk = blockIdx.x;             // b*64 + ntile
  int b = blk>>6, n0 = (blk&63)*64;
  int t = threadIdx.x;
  if (blk==0){
    for (int i=t;i<6144;i+=256) statz[i]=0.f;
  }
  #pragma unroll 4
  for (int i=0;i<32;i++){
    int idx = i*256 + t;
    int c = idx>>6, n = idx&63;
    tile[c][n] = ldin(feats, ((size_t)b*128 + c)*NPTS + n0 + n, f32);
  }
  __syncthreads();
  #pragma unroll 4
  for (int i=0;i<32;i++){
    int idx = i*256 + t;
    int n = idx>>7, c = idx&127;
    G[((size_t)b*NPTS + n0 + n)*136 + 3 + c] = (_Float16)tile[c][n];
  }
  if (t<64){
    size_t gb = ((size_t)b*NPTS + n0 + t)*136;
    G[gb]=(_Float16)0.f; G[gb+1]=(_Float16)0.f; G[gb+2]=(_Float16)0.f;
    #pragma unroll
    for (int c=131;c<136;c++) G[gb+c]=(_Float16)0.f;
  }
}

// ---------------------------------------------------------------------------
// MFMA conv: block = 128 pts x 128 outs, 4 waves at 64x64, K chunks of 32.
// mfma_f32_16x16x32_f16, f32 accumulate. LAYER 1: A from G (knn gather)+dxyz,
// K 131->160. LAYER 2/3: mu/rs computed inline from prev-layer sums, then
// A = relu((Hin-mu)*rs). Stats -> per-(b,o) f32 atomics. Biases cancel.
// ---------------------------------------------------------------------------
template<int LAYER>
__global__ __launch_bounds__(256) void conv_mfma(
    const void* __restrict__ pc1,
    const _Float16* __restrict__ G,
    const int* __restrict__ knn_idx,
    const float* __restrict__ new_xyz,
    const _Float16* __restrict__ Hin,
    const float* __restrict__ gp1,
    const float* __restrict__ gp2,
    const void* __restrict__ W,
    _Float16* __restrict__ Hout,
    float* __restrict__ gs1, float* __restrict__ gs2)
{
  constexpr int KC  = (LAYER==1)?131:128;
  constexpr int KCP = (LAYER==1)?160:128;
  constexpr int HSW = (LAYER==1)?168:136;
  __shared__ __align__(16) _Float16 hs[128][HSW];
  __shared__ __align__(16) _Float16 wt[128][40];
  __shared__ float red1[4][64], red2[4][64];
  __shared__ int   nidx[128];
  __shared__ float cxyz[4][3];
  __shared__ float smu[128], srs[128];
  int blk = blockIdx.x;
  int m0 = blk*128;
  int b  = m0 >> 15;
  int t  = threadIdx.x;
  const bool f32 = detect_f32((const unsigned short*)pc1);
  int w = t>>6, lane = t&63;
  int l16 = lane&15, q = lane>>4, q8 = q*8;
  int wr = (w&1)*64, wc = (w>>1)*64;

  if (LAYER==1){
    if (t<128) nidx[t] = knn_idx[m0+t];
    if (t<12)  cxyz[t/3][t%3] = new_xyz[(size_t)(m0>>5)*3 + t];
    __syncthreads();
    for (int u=t; u<128*17; u+=256){
      int p = u/17, qq = u - p*17;
      const f16x8* src = (const f16x8*)(G + ((size_t)b*NPTS + nidx[p])*136 + qq*8);
      *(f16x8*)&hs[p][qq*8] = *src;
    }
    for (int u=t; u<128*3; u+=256){
      int p = u/3, qq = u - p*3;
      uint4 z; z.x=z.y=z.z=z.w=0u;
      *(uint4*)&hs[p][136+qq*8] = z;
    }
    __syncthreads();
    if (t<128){
      int n = nidx[t];
      float cx = cxyz[t>>5][0], cy = cxyz[t>>5][1], cz = cxyz[t>>5][2];
      hs[t][0] = (_Float16)(ldin(pc1, ((size_t)b*3+0)*NPTS+n, f32) - cx);
      hs[t][1] = (_Float16)(ldin(pc1, ((size_t)b*3+1)*NPTS+n, f32) - cy);
      hs[t][2] = (_Float16)(ldin(pc1, ((size_t)b*3+2)*NPTS+n, f32) - cz);
    }
    __syncthreads();
  } else {
    if (t<128){
      const float inv = 1.0f/32768.0f;
      float m = gp1[b*128+t]*inv;
      smu[t] = m;
      srs[t] = rsqrtf(gp2[b*128+t]*inv - m*m + 1e-5f);
    }
    __syncthreads();
    int p = t & 127, hi = t>>7;
    const _Float16* src = Hin + (size_t)(m0+p)*128 + hi*64;
    #pragma unroll
    for (int j=0;j<8;j++){
      f16x8 v = *(const f16x8*)(src + j*8);
      f16x8 o;
      #pragma unroll
      for (int e=0;e<8;e++){
        int c = hi*64 + j*8 + e;
        float x = ((float)v[e] - smu[c]) * srs[c];
        o[e] = (_Float16)(x > 0.f ? x : 0.f);
      }
      *(f16x8*)&hs[p][hi*64 + j*8] = o;
    }
    __syncthreads();
  }

  f32x4 acc[4][4];
  #pragma unroll
  for (int i=0;i<4;i++)
    #pragma unroll
    for (int c=0;c<4;c++){ acc[i][c][0]=0.f; acc[i][c][1]=0.f; acc[i][c][2]=0.f; acc[i][c][3]=0.f; }

  for (int k0=0; k0<KCP; k0+=32){
    {
      int o = t>>1, half = t&1;
      f16x8 w0, w1;
      #pragma unroll
      for (int jj=0;jj<8;jj++){
        int c0 = k0 + half*16 + jj, c1 = c0 + 8;
        w0[jj] = (_Float16)((c0<KC) ? ldin(W, (size_t)o*KC + c0, f32) : 0.f);
        w1[jj] = (_Float16)((c1<KC) ? ldin(W, (size_t)o*KC + c1, f32) : 0.f);
      }
      *(f16x8*)&wt[o][half*16]     = w0;
      *(f16x8*)&wt[o][half*16 + 8] = w1;
    }
    __syncthreads();
    f16x8 av[4], bv[4];
    #pragma unroll
    for (int i=0;i<4;i++) av[i] = *(const f16x8*)&hs[wr + i*16 + l16][k0 + q8];
    #pragma unroll
    for (int c=0;c<4;c++) bv[c] = *(const f16x8*)&wt[wc + c*16 + l16][q8];
    #pragma unroll
    for (int i=0;i<4;i++)
      #pragma unroll
      for (int c=0;c<4;c++)
        acc[i][c] = __builtin_amdgcn_mfma_f32_16x16x32_f16(av[i], bv[c], acc[i][c], 0,0,0);
    __syncthreads();
  }

  #pragma unroll
  for (int c=0;c<4;c++){
    int o = wc + c*16 + l16;
    float s1=0.f, s2=0.f;
    #pragma unroll
    for (int i=0;i<4;i++){
      int row = wr + i*16 + q*4;
      #pragma unroll
      for (int r=0;r<4;r++){
        float v = acc[i][c][r];
        Hout[(size_t)(m0 + row + r)*128 + o] = (_Float16)v;
        s1 += v; s2 = fmaf(v,v,s2);
      }
    }
    s1 += __shfl_xor(s1, 16, 64); s1 += __shfl_xor(s1, 32, 64);
    s2 += __shfl_xor(s2, 16, 64); s2 += __shfl_xor(s2, 32, 64);
    if (q==0){ red1[w][c*16+l16] = s1; red2[w][c*16+l16] = s2; }
  }
  __syncthreads();
  if (t<128){
    int lo = t & 63, g = (t>>6)*2;
    unsafeAtomicAdd(&gs1[b*128+t], red1[g][lo] + red1[g+1][lo]);
    unsafeAtomicAdd(&gs2[b*128+t], red2[g][lo] + red2[g+1][lo]);
  }
}

// ---------------------------------------------------------------------------
// Final: per (b,s): mu/rs from layer-3 sums, norm+relu, max over K, fc 128->3
// ---------------------------------------------------------------------------
__global__ __launch_bounds__(128) void final_kernel(
    const void* __restrict__ pc1,
    const _Float16* __restrict__ H,
    const float* __restrict__ gp1, const float* __restrict__ gp2,
    const void* __restrict__ fc_w, const void* __restrict__ fc_b,
    void* __restrict__ outv)
{
  int blk = blockIdx.x;       // b*1024+s
  int b = blk>>10, s = blk & 1023;
  int o = threadIdx.x;
  const bool f32 = detect_f32((const unsigned short*)pc1);
  int bo = b*128 + o;
  const float inv = 1.0f/32768.0f;
  float mu_ = gp1[bo]*inv;
  float rs_ = rsqrtf(gp2[bo]*inv - mu_*mu_ + 1e-5f);
  const _Float16* hp = H + (size_t)blk*NK*128 + o;
  float m = -1e30f;
  #pragma unroll 4
  for(int k=0;k<NK;k++){
    float v = ((float)hp[(size_t)k*128] - mu_)*rs_;
    m = fmaxf(m, v);
  }
  m = fmaxf(m, 0.f);
  __shared__ float mv[128];
  mv[o] = m;
  __syncthreads();
  if (o<3){
    float acc = ldin(fc_b, o, f32);
    for(int c=0;c<128;c++) acc = fmaf(ldin(fc_w, (size_t)o*128+c, f32), mv[c], acc);
    size_t oi = ((size_t)b*3 + o)*NS + s;
    if (f32) ((float*)outv)[oi] = acc;
    else     ((unsigned short*)outv)[oi] = f2bf(acc);
  }
}

// ---------------------------------------------------------------------------
extern "C" void kernel_launch(void* const* d_in, const int* in_sizes, int n_in,
                              void* d_out, int out_size, void* d_ws, size_t ws_size,
                              hipStream_t stream){
  const void* pc1   = d_in[0];
  const void* feats = d_in[1];
  const void* W1    = d_in[2];
  const void* W2    = d_in[4];
  const void* W3    = d_in[6];
  const void* fcw   = d_in[8];
  const void* fcb   = d_in[9];
  char* ws = (char*)d_ws;
  int*      fps  = (int*)     (ws + 0);          // 32768 B
  float*    nxyz = (float*)   (ws + 32768);      // 98304 B
  int*      knn  = (int*)     (ws + 131072);     // 1048576 B
  float*    st   = (float*)   (ws + 1179648);    // 6*1024*4 = 24576 B  [s1a s2a s1b s2b s1c s2c]
  _Float16* Ha   = (_Float16*)(ws + 1204224);    // 67108864 B
  _Float16* Hb   = (_Float16*)(ws + 68313088);   // 67108864 B (total 135421952)
  _Float16* G    = Hb;  // G (8.9 MB) aliases Hb: read only by conv1, Hb first written by conv2

  feat_transpose<<<NB*64, 256, 0, stream>>>(feats, pc1, G, st);
  fps_kernel<<<NB, 256, 0, stream>>>(pc1, fps);
  knn_kernel<<<NB*NS, 256, 0, stream>>>(pc1, fps, nxyz, knn);

  conv_mfma<1><<<NM/128, 256, 0, stream>>>(pc1, G, knn, nxyz,
      (const _Float16*)nullptr, (const float*)nullptr, (const float*)nullptr,
      W1, Ha, st, st+1024);
  conv_mfma<2><<<NM/128, 256, 0, stream>>>(pc1, G, knn, nxyz,
      Ha, st, st+1024, W2, Hb, st+2048, st+3072);
  conv_mfma<3><<<NM/128, 256, 0, stream>>>(pc1, G, knn, nxyz,
      Hb, st+2048, st+3072, W3, Ha, st+4096, st+5120);

  final_kernel<<<NB*NS, 128, 0, stream>>>(pc1, Ha, st+4096, st+5120, fcw, fcb, d_out);
}

// Round 13
// 1092.703 us; speedup vs baseline: 1.2035x; 1.1048x over previous
//
#include <hip/hip_runtime.h>
#include <hip/hip_fp16.h>

#define NB 8
#define NPTS 4096
#define NS 1024
#define NK 32
#define NM (NB*NS*NK)   // 262144 grouped points

typedef _Float16 f16x8 __attribute__((ext_vector_type(8)));
typedef float    f32x4 __attribute__((ext_vector_type(4)));
typedef float    f32x2 __attribute__((ext_vector_type(2)));

__device__ __forceinline__ float bf2f(unsigned short u){ return __uint_as_float(((unsigned)u)<<16); }
__device__ __forceinline__ unsigned short f2bf(float f){
  unsigned u = __float_as_uint(f);
  u = u + 0x7fffu + ((u>>16)&1u);   // RNE
  return (unsigned short)(u>>16);
}
__device__ __forceinline__ unsigned long long umax64(unsigned long long a, unsigned long long b){ return a>b?a:b; }
__device__ __forceinline__ unsigned long long umin64(unsigned long long a, unsigned long long b){ return a<b?a:b; }
__device__ __forceinline__ unsigned umin3u(unsigned a, unsigned b, unsigned c){
  unsigned m = a<b?a:b; return m<c?m:c;   // -> v_min3_u32
}

// ---- DPP wave64 reduce: row_shr 1/2/4/8 + row_bcast 15/31, result in lane 63.
#define DPP_STEP_MAX(x, ctrl, rm) { \
  unsigned _t = (unsigned)__builtin_amdgcn_update_dpp((int)(x), (int)(x), (ctrl), (rm), 0xf, false); \
  (x) = ((x) > _t) ? (x) : _t; }
#define DPP_STEP_MIN(x, ctrl, rm) { \
  unsigned _t = (unsigned)__builtin_amdgcn_update_dpp((int)(x), (int)(x), (ctrl), (rm), 0xf, false); \
  (x) = ((x) < _t) ? (x) : _t; }

__device__ __forceinline__ unsigned wave_max_u32(unsigned x){
  DPP_STEP_MAX(x, 0x111, 0xf);
  DPP_STEP_MAX(x, 0x112, 0xf);
  DPP_STEP_MAX(x, 0x114, 0xf);
  DPP_STEP_MAX(x, 0x118, 0xf);
  DPP_STEP_MAX(x, 0x142, 0xa);
  DPP_STEP_MAX(x, 0x143, 0xc);
  return (unsigned)__builtin_amdgcn_readlane((int)x, 63);
}
__device__ __forceinline__ unsigned wave_min_u32(unsigned x){
  DPP_STEP_MIN(x, 0x111, 0xf);
  DPP_STEP_MIN(x, 0x112, 0xf);
  DPP_STEP_MIN(x, 0x114, 0xf);
  DPP_STEP_MIN(x, 0x118, 0xf);
  DPP_STEP_MIN(x, 0x142, 0xa);
  DPP_STEP_MIN(x, 0x143, 0xc);
  return (unsigned)__builtin_amdgcn_readlane((int)x, 63);
}

// Runtime dtype detection (block-uniform scalar branch): f32 data read as bf16
// halves decodes huge/denormal or exact-zero; true bf16 N(0,1) does not.
__device__ __forceinline__ bool detect_f32(const unsigned short* __restrict__ u){
  int huge_=0, zero_=0;
  #pragma unroll
  for (int i=0;i<64;i++){
    unsigned short w = u[i];
    if ((w & 0x7fffu) == 0) { zero_++; continue; }
    float a = fabsf(bf2f(w));
    if (a > 1e6f || a < 1e-6f) huge_++;
  }
  return (huge_ >= 8) || (zero_ >= 24);
}
__device__ __forceinline__ float ldin(const void* p, size_t i, bool f32){
  if (f32) return ((const float*)p)[i];
  else     return bf2f(((const unsigned short*)p)[i]);
}

// ---------------------------------------------------------------------------
// FPS (round-10 verbatim, measured 531 us). 66KB LDS caps occupancy at 1
// block/CU -> allocator keeps arrays register-resident (VGPR 88).
// ---------------------------------------------------------------------------
__global__ __launch_bounds__(256) void fps_kernel(const void* __restrict__ pc1,
                                                  int* __restrict__ fps_out){
  __shared__ __align__(16) float4 cp4[NPTS];
  __shared__ __align__(16) unsigned long long part[2][4];
  int b = blockIdx.x, t = threadIdx.x;
  const bool f32 = detect_f32((const unsigned short*)pc1);
  const size_t base = (size_t)b*3*NPTS;
  for (int i=t;i<NPTS;i+=256){
    float4 v;
    v.x = ldin(pc1, base+i, f32);
    v.y = ldin(pc1, base+NPTS+i, f32);
    v.z = ldin(pc1, base+2*NPTS+i, f32);
    v.w = 0.f;
    cp4[i] = v;
  }
  __syncthreads();
  f32x2 px[8],py[8],pz[8],dist[8];
  #pragma unroll
  for (int j=0;j<8;j++){
    float4 a = cp4[t*16+2*j], c = cp4[t*16+2*j+1];
    px[j] = f32x2{a.x, c.x};
    py[j] = f32x2{a.y, c.y};
    pz[j] = f32x2{a.z, c.z};
    dist[j] = f32x2{1e10f, 1e10f};
  }
  int far = 0;
  int w = t>>6, lane = t&63;
  for (int it=0; it<NS; it++){
    if (t==0) fps_out[b*NS+it] = far;
    float4 cc = cp4[far];
    f32x2 vcx = f32x2{cc.x,cc.x}, vcy = f32x2{cc.y,cc.y}, vcz = f32x2{cc.z,cc.z};
    {
      #pragma clang fp contract(off)
      #pragma unroll
      for (int j=0;j<8;j++){
        f32x2 dx = px[j]-vcx, dy = py[j]-vcy, dz = pz[j]-vcz;
        f32x2 d  = (dx*dx + dy*dy) + dz*dz;     // exact RN order: ((x2+y2)+z2)
        dist[j]  = __builtin_elementwise_min(dist[j], d);
      }
    }
    float d_[16];
    #pragma unroll
    for (int j=0;j<8;j++){ d_[2*j]=dist[j][0]; d_[2*j+1]=dist[j][1]; }
    float a0 = fmaxf(fmaxf(d_[0],d_[1]),d_[2]);      // -> v_max3_f32
    float a1 = fmaxf(fmaxf(d_[3],d_[4]),d_[5]);
    float a2 = fmaxf(fmaxf(d_[6],d_[7]),d_[8]);
    float a3 = fmaxf(fmaxf(d_[9],d_[10]),d_[11]);
    float a4 = fmaxf(fmaxf(d_[12],d_[13]),d_[14]);
    float b0 = fmaxf(fmaxf(a0,a1),a2);
    float b1 = fmaxf(fmaxf(a3,a4),d_[15]);
    float bl = fmaxf(b0,b1);
    int li = 0;
    #pragma unroll
    for (int i=15;i>=0;i--) if (d_[i]==bl) li = i;   // descending: final = lowest i
    unsigned blu = __float_as_uint(bl);               // dist>=0: bits monotone
    unsigned wm = wave_max_u32(blu);
    unsigned long long mk = __ballot(blu == wm);
    int l = __builtin_ctzll(mk);                      // lowest lane = lowest n
    int idx = __builtin_amdgcn_readlane(t*16+li, l);
    if (lane==0) part[it&1][w] = ((unsigned long long)wm<<32) | (unsigned)(NPTS-1-idx);
    __syncthreads();
    const ulonglong2* pp = (const ulonglong2*)&part[it&1][0];
    ulonglong2 A = pp[0], B = pp[1];
    unsigned long long m = umax64(umax64(A.x,A.y), umax64(B.x,B.y));
    far = NPTS-1 - (int)(m & 0xffffffffu);
  }
}

// ---------------------------------------------------------------------------
// kNN v3 (round-10 verbatim — r12's all-register v4 was 25 us SLOWER: knn is
// VALU-issue-bound, v3's cached 4-group minima + cheap LDS patch wins).
// ---------------------------------------------------------------------------
__global__ __launch_bounds__(256) void knn_kernel(const void* __restrict__ pc1,
                                                  const int* __restrict__ fps_idx,
                                                  float* __restrict__ new_xyz,
                                                  int* __restrict__ knn_idx){
  __shared__ __align__(16) unsigned dbs[256*20];                 // 20 KB
  __shared__ __align__(16) unsigned long long lists[4][NK];      // 1 KB
  int blk = blockIdx.x;   // b*1024 + s
  int b = blk >> 10;
  int t = threadIdx.x;
  int w = t>>6, lane = t&63;
  const bool f32 = detect_f32((const unsigned short*)pc1);
  const size_t base = (size_t)b*3*NPTS;
  int n0 = fps_idx[blk];
  float qx = ldin(pc1, base+n0, f32);
  float qy = ldin(pc1, base+NPTS+n0, f32);
  float qz = ldin(pc1, base+2*NPTS+n0, f32);
  if (t==0){ new_xyz[(size_t)blk*3]=qx; new_xyz[(size_t)blk*3+1]=qy; new_xyz[(size_t)blk*3+2]=qz; }
  float qn = __fadd_rn(__fadd_rn(__fmul_rn(qx,qx),__fmul_rn(qy,qy)),__fmul_rn(qz,qz));
  #pragma unroll
  for (int k=0;k<16;k++){
    int n = t + 256*k;                               // coalesced global reads
    float x = ldin(pc1, base+n, f32);
    float y = ldin(pc1, base+NPTS+n, f32);
    float z = ldin(pc1, base+2*NPTS+n, f32);
    float pn = __fadd_rn(__fadd_rn(__fmul_rn(x,x),__fmul_rn(y,y)),__fmul_rn(z,z));
    float dt = __fadd_rn(__fadd_rn(__fmul_rn(qx,x),__fmul_rn(qy,y)),__fmul_rn(qz,z));
    float d  = __fsub_rn(__fadd_rn(qn,pn), __fmul_rn(2.f,dt));
    unsigned u = __float_as_uint(d);
    u = (u & 0x80000000u) ? ~u : (u | 0x80000000u);  // order-preserving map
    dbs[(n>>4)*20 + (n&15)] = u;                     // transpose to owner layout
  }
  __syncthreads();
  unsigned gm[4]; int gj[4];
  #pragma unroll
  for (int g=0; g<4; g++){
    uint4 v = *(const uint4*)&dbs[t*20 + 4*g];
    unsigned m = v.x; int j = 0;
    if (v.y < m){ m = v.y; j = 1; }                  // strict <, ascending: first min
    if (v.z < m){ m = v.z; j = 2; }
    if (v.w < m){ m = v.w; j = 3; }
    gm[g] = m; gj[g] = j;
  }
  #pragma unroll 1
  for (int r=0; r<NK; r++){
    unsigned bl = umin3u(gm[0],gm[1],gm[2]);
    bl = bl < gm[3] ? bl : gm[3];
    int bg = 3;                                      // descending: final = lowest g
    if (gm[2]==bl) bg=2;
    if (gm[1]==bl) bg=1;
    if (gm[0]==bl) bg=0;
    int lj = gj[0];
    if (bg==1) lj=gj[1];
    if (bg==2) lj=gj[2];
    if (bg==3) lj=gj[3];
    int bn = (t<<4) + (bg<<2) + lj;                  // global point idx
    uint4 gv = *(const uint4*)&dbs[t*20 + (bg<<2)];  // speculative reload
    unsigned wm = wave_min_u32(bl);
    unsigned long long mk = __ballot(bl == wm);
    int l = __builtin_ctzll(mk);                     // lowest lane = lowest idx on tie
    int idx = __builtin_amdgcn_readlane(bn, l);
    if (lane==0) lists[w][r] = ((unsigned long long)wm<<32) | (unsigned)idx;
    if (lane==l){
      unsigned g0 = (lj==0)?0xFFFFFFFFu:gv.x;
      unsigned g1 = (lj==1)?0xFFFFFFFFu:gv.y;
      unsigned g2 = (lj==2)?0xFFFFFFFFu:gv.z;
      unsigned g3 = (lj==3)?0xFFFFFFFFu:gv.w;
      uint4 nv; nv.x=g0; nv.y=g1; nv.z=g2; nv.w=g3;
      *(uint4*)&dbs[t*20 + (bg<<2)] = nv;
      unsigned m = g0; int j = 0;
      if (g1 < m){ m=g1; j=1; }
      if (g2 < m){ m=g2; j=2; }
      if (g3 < m){ m=g3; j=3; }
      if (bg==0){ gm[0]=m; gj[0]=j; }
      if (bg==1){ gm[1]=m; gj[1]=j; }
      if (bg==2){ gm[2]=m; gj[2]=j; }
      if (bg==3){ gm[3]=m; gj[3]=j; }
    }
  }
  __syncthreads();
  if (t < 128){
    int cl = t>>5, p = t&31;
    unsigned long long K = lists[cl][p];
    int rank = p;                                    // lists strictly increasing
    #pragma unroll
    for (int ol=0; ol<4; ol++){
      if (ol==cl) continue;
      int lo = 0;                                    // count of elems < K
      if (lists[ol][15]    < K) lo  = 16;
      if (lists[ol][lo+7]  < K) lo += 8;
      if (lists[ol][lo+3]  < K) lo += 4;
      if (lists[ol][lo+1]  < K) lo += 2;
      if (lists[ol][lo]    < K) lo += 1;
      rank += lo;
    }
    if (rank < NK) knn_idx[(size_t)blk*NK + rank] = (int)(K & 0xffffffffu);
  }
}

// ---------------------------------------------------------------------------
// feats [B,128,N] (f32/bf16) -> G [B,N,136] fp16; block 0 also zeroes the six
// stat buffers (6144 f32) so no memset nodes are needed (ws is 0xAA-poisoned).
// ---------------------------------------------------------------------------
__global__ __launch_bounds__(256) void feat_transpose(const void* __restrict__ feats,
                                                      const void* __restrict__ pc1,
                                                      _Float16* __restrict__ G,
                                                      float* __restrict__ statz){
  __shared__ float tile[128][65];
  const bool f32 = detect_f32((const unsigned short*)pc1);
  int blk = blockIdx.x;             // b*64 + ntile
  int b = blk>>6, n0 = (blk&63)*64;
  int t = threadIdx.x;
  if (blk==0){
    for (int i=t;i<6144;i+=256) statz[i]=0.f;
  }
  #pragma unroll 4
  for (int i=0;i<32;i++){
    int idx = i*256 + t;
    int c = idx>>6, n = idx&63;
    tile[c][n] = ldin(feats, ((size_t)b*128 + c)*NPTS + n0 + n, f32);
  }
  __syncthreads();
  #pragma unroll 4
  for (int i=0;i<32;i++){
    int idx = i*256 + t;
    int n = idx>>7, c = idx&127;
    G[((size_t)b*NPTS + n0 + n)*136 + 3 + c] = (_Float16)tile[c][n];
  }
  if (t<64){
    size_t gb = ((size_t)b*NPTS + n0 + t)*136;
    G[gb]=(_Float16)0.f; G[gb+1]=(_Float16)0.f; G[gb+2]=(_Float16)0.f;
    #pragma unroll
    for (int c=131;c<136;c++) G[gb+c]=(_Float16)0.f;
  }
}

// ---------------------------------------------------------------------------
// MFMA conv: block = 128 pts x 128 outs, 4 waves at 64x64, K chunks of 32.
// R13 changes vs r10: (a) epilogue routes C through hs (LDS) then coalesced
// f16x8 global stores (was 64 scalar global_store_short/thread, ~128B useful
// per instr); (b) layer-2/3 norm+relu staging in packed f16 (v_pk ops, mu/rs
// pre-rounded to f16 — adds <=2e-3 abs err, threshold slack 4x);
// (c) float4-vectorized W staging for aligned (f32, KC=128) layers.
// ---------------------------------------------------------------------------
template<int LAYER>
__global__ __launch_bounds__(256) void conv_mfma(
    const void* __restrict__ pc1,
    const _Float16* __restrict__ G,
    const int* __restrict__ knn_idx,
    const float* __restrict__ new_xyz,
    const _Float16* __restrict__ Hin,
    const float* __restrict__ gp1,
    const float* __restrict__ gp2,
    const void* __restrict__ W,
    _Float16* __restrict__ Hout,
    float* __restrict__ gs1, float* __restrict__ gs2)
{
  constexpr int KC  = (LAYER==1)?131:128;
  constexpr int KCP = (LAYER==1)?160:128;
  constexpr int HSW = (LAYER==1)?168:136;
  __shared__ __align__(16) _Float16 hs[128][HSW];
  __shared__ __align__(16) _Float16 wt[128][40];
  __shared__ float red1[4][64], red2[4][64];
  __shared__ int   nidx[128];
  __shared__ float cxyz[4][3];
  __shared__ __align__(16) _Float16 smuh[128], srsh[128];
  int blk = blockIdx.x;
  int m0 = blk*128;
  int b  = m0 >> 15;
  int t  = threadIdx.x;
  const bool f32 = detect_f32((const unsigned short*)pc1);
  int w = t>>6, lane = t&63;
  int l16 = lane&15, q = lane>>4, q8 = q*8;
  int wr = (w&1)*64, wc = (w>>1)*64;

  if (LAYER==1){
    if (t<128) nidx[t] = knn_idx[m0+t];
    if (t<12)  cxyz[t/3][t%3] = new_xyz[(size_t)(m0>>5)*3 + t];
    __syncthreads();
    for (int u=t; u<128*17; u+=256){
      int p = u/17, qq = u - p*17;
      const f16x8* src = (const f16x8*)(G + ((size_t)b*NPTS + nidx[p])*136 + qq*8);
      *(f16x8*)&hs[p][qq*8] = *src;
    }
    for (int u=t; u<128*3; u+=256){
      int p = u/3, qq = u - p*3;
      uint4 z; z.x=z.y=z.z=z.w=0u;
      *(uint4*)&hs[p][136+qq*8] = z;
    }
    __syncthreads();
    if (t<128){
      int n = nidx[t];
      float cx = cxyz[t>>5][0], cy = cxyz[t>>5][1], cz = cxyz[t>>5][2];
      hs[t][0] = (_Float16)(ldin(pc1, ((size_t)b*3+0)*NPTS+n, f32) - cx);
      hs[t][1] = (_Float16)(ldin(pc1, ((size_t)b*3+1)*NPTS+n, f32) - cy);
      hs[t][2] = (_Float16)(ldin(pc1, ((size_t)b*3+2)*NPTS+n, f32) - cz);
    }
    __syncthreads();
  } else {
    if (t<128){
      const float inv = 1.0f/32768.0f;
      float m = gp1[b*128+t]*inv;
      smuh[t] = (_Float16)m;
      srsh[t] = (_Float16)rsqrtf(gp2[b*128+t]*inv - m*m + 1e-5f);
    }
    __syncthreads();
    int p = t & 127, hi = t>>7;
    const _Float16* src = Hin + (size_t)(m0+p)*128 + hi*64;
    f16x8 zero8 = {};
    #pragma unroll
    for (int j=0;j<8;j++){
      f16x8 v   = *(const f16x8*)(src + j*8);
      f16x8 mu8 = *(const f16x8*)&smuh[hi*64 + j*8];
      f16x8 rs8 = *(const f16x8*)&srsh[hi*64 + j*8];
      f16x8 o = (v - mu8) * rs8;                    // v_pk_*_f16
      o = __builtin_elementwise_max(o, zero8);      // relu
      *(f16x8*)&hs[p][hi*64 + j*8] = o;
    }
    __syncthreads();
  }

  f32x4 acc[4][4];
  #pragma unroll
  for (int i=0;i<4;i++)
    #pragma unroll
    for (int c=0;c<4;c++){ acc[i][c][0]=0.f; acc[i][c][1]=0.f; acc[i][c][2]=0.f; acc[i][c][3]=0.f; }

  for (int k0=0; k0<KCP; k0+=32){
    {
      int o = t>>1, half = t&1;
      f16x8 w0, w1;
      if (f32 && LAYER!=1){
        const float4* Wf = (const float4*)((const float*)W + (size_t)o*KC + k0 + half*16);
        float4 v0 = Wf[0], v1 = Wf[1], v2 = Wf[2], v3 = Wf[3];
        w0[0]=(_Float16)v0.x; w0[1]=(_Float16)v0.y; w0[2]=(_Float16)v0.z; w0[3]=(_Float16)v0.w;
        w0[4]=(_Float16)v1.x; w0[5]=(_Float16)v1.y; w0[6]=(_Float16)v1.z; w0[7]=(_Float16)v1.w;
        w1[0]=(_Float16)v2.x; w1[1]=(_Float16)v2.y; w1[2]=(_Float16)v2.z; w1[3]=(_Float16)v2.w;
        w1[4]=(_Float16)v3.x; w1[5]=(_Float16)v3.y; w1[6]=(_Float16)v3.z; w1[7]=(_Float16)v3.w;
      } else {
        #pragma unroll
        for (int jj=0;jj<8;jj++){
          int c0 = k0 + half*16 + jj, c1 = c0 + 8;
          w0[jj] = (_Float16)((c0<KC) ? ldin(W, (size_t)o*KC + c0, f32) : 0.f);
          w1[jj] = (_Float16)((c1<KC) ? ldin(W, (size_t)o*KC + c1, f32) : 0.f);
        }
      }
      *(f16x8*)&wt[o][half*16]     = w0;
      *(f16x8*)&wt[o][half*16 + 8] = w1;
    }
    __syncthreads();
    f16x8 av[4], bv[4];
    #pragma unroll
    for (int i=0;i<4;i++) av[i] = *(const f16x8*)&hs[wr + i*16 + l16][k0 + q8];
    #pragma unroll
    for (int c=0;c<4;c++) bv[c] = *(const f16x8*)&wt[wc + c*16 + l16][q8];
    #pragma unroll
    for (int i=0;i<4;i++)
      #pragma unroll
      for (int c=0;c<4;c++)
        acc[i][c] = __builtin_amdgcn_mfma_f32_16x16x32_f16(av[i], bv[c], acc[i][c], 0,0,0);
    __syncthreads();
  }

  // epilogue: stats from f32 acc (unchanged math) + C -> hs (f16) -> coalesced
  #pragma unroll
  for (int c=0;c<4;c++){
    int o = wc + c*16 + l16;
    float s1=0.f, s2=0.f;
    #pragma unroll
    for (int i=0;i<4;i++){
      int row = wr + i*16 + q*4;
      #pragma unroll
      for (int r=0;r<4;r++){
        float v = acc[i][c][r];
        hs[row + r][o] = (_Float16)v;
        s1 += v; s2 = fmaf(v,v,s2);
      }
    }
    s1 += __shfl_xor(s1, 16, 64); s1 += __shfl_xor(s1, 32, 64);
    s2 += __shfl_xor(s2, 16, 64); s2 += __shfl_xor(s2, 32, 64);
    if (q==0){ red1[w][c*16+l16] = s1; red2[w][c*16+l16] = s2; }
  }
  __syncthreads();
  // coalesced store: chunk fi = j*256+t covers flat half-range [fi*8, fi*8+8)
  _Float16* dst0 = Hout + (size_t)m0*128;
  #pragma unroll
  for (int j=0;j<8;j++){
    int fi = j*256 + t;
    int row = fi >> 4, col = (fi & 15)*8;
    *(f16x8*)(dst0 + (size_t)fi*8) = *(const f16x8*)&hs[row][col];
  }
  if (t<128){
    int lo = t & 63, g = (t>>6)*2;
    unsafeAtomicAdd(&gs1[b*128+t], red1[g][lo] + red1[g+1][lo]);
    unsafeAtomicAdd(&gs2[b*128+t], red2[g][lo] + red2[g+1][lo]);
  }
}

// ---------------------------------------------------------------------------
// Final: per (b,s): mu/rs from layer-3 sums, norm+relu, max over K, fc 128->3
// ---------------------------------------------------------------------------
__global__ __launch_bounds__(128) void final_kernel(
    const void* __restrict__ pc1,
    const _Float16* __restrict__ H,
    const float* __restrict__ gp1, const float* __restrict__ gp2,
    const void* __restrict__ fc_w, const void* __restrict__ fc_b,
    void* __restrict__ outv)
{
  int blk = blockIdx.x;       // b*1024+s
  int b = blk>>10, s = blk & 1023;
  int o = threadIdx.x;
  const bool f32 = detect_f32((const unsigned short*)pc1);
  int bo = b*128 + o;
  const float inv = 1.0f/32768.0f;
  float mu_ = gp1[bo]*inv;
  float rs_ = rsqrtf(gp2[bo]*inv - mu_*mu_ + 1e-5f);
  const _Float16* hp = H + (size_t)blk*NK*128 + o;
  float m = -1e30f;
  #pragma unroll 4
  for(int k=0;k<NK;k++){
    float v = ((float)hp[(size_t)k*128] - mu_)*rs_;
    m = fmaxf(m, v);
  }
  m = fmaxf(m, 0.f);
  __shared__ float mv[128];
  mv[o] = m;
  __syncthreads();
  if (o<3){
    float acc = ldin(fc_b, o, f32);
    for(int c=0;c<128;c++) acc = fmaf(ldin(fc_w, (size_t)o*128+c, f32), mv[c], acc);
    size_t oi = ((size_t)b*3 + o)*NS + s;
    if (f32) ((float*)outv)[oi] = acc;
    else     ((unsigned short*)outv)[oi] = f2bf(acc);
  }
}

// ---------------------------------------------------------------------------
extern "C" void kernel_launch(void* const* d_in, const int* in_sizes, int n_in,
                              void* d_out, int out_size, void* d_ws, size_t ws_size,
                              hipStream_t stream){
  const void* pc1   = d_in[0];
  const void* feats = d_in[1];
  const void* W1    = d_in[2];
  const void* W2    = d_in[4];
  const void* W3    = d_in[6];
  const void* fcw   = d_in[8];
  const void* fcb   = d_in[9];
  char* ws = (char*)d_ws;
  int*      fps  = (int*)     (ws + 0);          // 32768 B
  float*    nxyz = (float*)   (ws + 32768);      // 98304 B
  int*      knn  = (int*)     (ws + 131072);     // 1048576 B
  float*    st   = (float*)   (ws + 1179648);    // 6*1024*4 = 24576 B  [s1a s2a s1b s2b s1c s2c]
  _Float16* Ha   = (_Float16*)(ws + 1204224);    // 67108864 B
  _Float16* Hb   = (_Float16*)(ws + 68313088);   // 67108864 B (total 135421952)
  _Float16* G    = Hb;  // G (8.9 MB) aliases Hb: read only by conv1, Hb first written by conv2

  feat_transpose<<<NB*64, 256, 0, stream>>>(feats, pc1, G, st);
  fps_kernel<<<NB, 256, 0, stream>>>(pc1, fps);
  knn_kernel<<<NB*NS, 256, 0, stream>>>(pc1, fps, nxyz, knn);

  conv_mfma<1><<<NM/128, 256, 0, stream>>>(pc1, G, knn, nxyz,
      (const _Float16*)nullptr, (const float*)nullptr, (const float*)nullptr,
      W1, Ha, st, st+1024);
  conv_mfma<2><<<NM/128, 256, 0, stream>>>(pc1, G, knn, nxyz,
      Ha, st, st+1024, W2, Hb, st+2048, st+3072);
  conv_mfma<3><<<NM/128, 256, 0, stream>>>(pc1, G, knn, nxyz,
      Hb, st+2048, st+3072, W3, Ha, st+4096, st+5120);

  final_kernel<<<NB*NS, 128, 0, stream>>>(pc1, Ha, st+4096, st+5120, fcw, fcb, d_out);
}

// Round 14
// 1059.409 us; speedup vs baseline: 1.2413x; 1.0314x over previous
//
#include <hip/hip_runtime.h>
#include <hip/hip_fp16.h>

#define NB 8
#define NPTS 4096
#define NS 1024
#define NK 32
#define NM (NB*NS*NK)   // 262144 grouped points

typedef _Float16 f16x8 __attribute__((ext_vector_type(8)));
typedef float    f32x4 __attribute__((ext_vector_type(4)));
typedef float    f32x2 __attribute__((ext_vector_type(2)));

__device__ __forceinline__ float bf2f(unsigned short u){ return __uint_as_float(((unsigned)u)<<16); }
__device__ __forceinline__ unsigned short f2bf(float f){
  unsigned u = __float_as_uint(f);
  u = u + 0x7fffu + ((u>>16)&1u);   // RNE
  return (unsigned short)(u>>16);
}
__device__ __forceinline__ unsigned long long umax64(unsigned long long a, unsigned long long b){ return a>b?a:b; }

// ---- DPP wave64 reduce: row_shr 1/2/4/8 + row_bcast 15/31, result in lane 63.
#define DPP_STEP_MAX(x, ctrl, rm) { \
  unsigned _t = (unsigned)__builtin_amdgcn_update_dpp((int)(x), (int)(x), (ctrl), (rm), 0xf, false); \
  (x) = ((x) > _t) ? (x) : _t; }

__device__ __forceinline__ unsigned wave_max_u32(unsigned x){
  DPP_STEP_MAX(x, 0x111, 0xf);
  DPP_STEP_MAX(x, 0x112, 0xf);
  DPP_STEP_MAX(x, 0x114, 0xf);
  DPP_STEP_MAX(x, 0x118, 0xf);
  DPP_STEP_MAX(x, 0x142, 0xa);
  DPP_STEP_MAX(x, 0x143, 0xc);
  return (unsigned)__builtin_amdgcn_readlane((int)x, 63);
}

// Runtime dtype detection (block-uniform scalar branch): f32 data read as bf16
// halves decodes huge/denormal or exact-zero; true bf16 N(0,1) does not.
__device__ __forceinline__ bool detect_f32(const unsigned short* __restrict__ u){
  int huge_=0, zero_=0;
  #pragma unroll
  for (int i=0;i<64;i++){
    unsigned short w = u[i];
    if ((w & 0x7fffu) == 0) { zero_++; continue; }
    float a = fabsf(bf2f(w));
    if (a > 1e6f || a < 1e-6f) huge_++;
  }
  return (huge_ >= 8) || (zero_ >= 24);
}
__device__ __forceinline__ float ldin(const void* p, size_t i, bool f32){
  if (f32) return ((const float*)p)[i];
  else     return bf2f(((const unsigned short*)p)[i]);
}

// ---------------------------------------------------------------------------
// FPS (round-10 verbatim, measured 531 us). 66KB LDS caps occupancy at 1
// block/CU -> allocator keeps arrays register-resident (VGPR 88).
// ---------------------------------------------------------------------------
__global__ __launch_bounds__(256) void fps_kernel(const void* __restrict__ pc1,
                                                  int* __restrict__ fps_out){
  __shared__ __align__(16) float4 cp4[NPTS];
  __shared__ __align__(16) unsigned long long part[2][4];
  int b = blockIdx.x, t = threadIdx.x;
  const bool f32 = detect_f32((const unsigned short*)pc1);
  const size_t base = (size_t)b*3*NPTS;
  for (int i=t;i<NPTS;i+=256){
    float4 v;
    v.x = ldin(pc1, base+i, f32);
    v.y = ldin(pc1, base+NPTS+i, f32);
    v.z = ldin(pc1, base+2*NPTS+i, f32);
    v.w = 0.f;
    cp4[i] = v;
  }
  __syncthreads();
  f32x2 px[8],py[8],pz[8],dist[8];
  #pragma unroll
  for (int j=0;j<8;j++){
    float4 a = cp4[t*16+2*j], c = cp4[t*16+2*j+1];
    px[j] = f32x2{a.x, c.x};
    py[j] = f32x2{a.y, c.y};
    pz[j] = f32x2{a.z, c.z};
    dist[j] = f32x2{1e10f, 1e10f};
  }
  int far = 0;
  int w = t>>6, lane = t&63;
  for (int it=0; it<NS; it++){
    if (t==0) fps_out[b*NS+it] = far;
    float4 cc = cp4[far];
    f32x2 vcx = f32x2{cc.x,cc.x}, vcy = f32x2{cc.y,cc.y}, vcz = f32x2{cc.z,cc.z};
    {
      #pragma clang fp contract(off)
      #pragma unroll
      for (int j=0;j<8;j++){
        f32x2 dx = px[j]-vcx, dy = py[j]-vcy, dz = pz[j]-vcz;
        f32x2 d  = (dx*dx + dy*dy) + dz*dz;     // exact RN order: ((x2+y2)+z2)
        dist[j]  = __builtin_elementwise_min(dist[j], d);
      }
    }
    float d_[16];
    #pragma unroll
    for (int j=0;j<8;j++){ d_[2*j]=dist[j][0]; d_[2*j+1]=dist[j][1]; }
    float a0 = fmaxf(fmaxf(d_[0],d_[1]),d_[2]);      // -> v_max3_f32
    float a1 = fmaxf(fmaxf(d_[3],d_[4]),d_[5]);
    float a2 = fmaxf(fmaxf(d_[6],d_[7]),d_[8]);
    float a3 = fmaxf(fmaxf(d_[9],d_[10]),d_[11]);
    float a4 = fmaxf(fmaxf(d_[12],d_[13]),d_[14]);
    float b0 = fmaxf(fmaxf(a0,a1),a2);
    float b1 = fmaxf(fmaxf(a3,a4),d_[15]);
    float bl = fmaxf(b0,b1);
    int li = 0;
    #pragma unroll
    for (int i=15;i>=0;i--) if (d_[i]==bl) li = i;   // descending: final = lowest i
    unsigned blu = __float_as_uint(bl);               // dist>=0: bits monotone
    unsigned wm = wave_max_u32(blu);
    unsigned long long mk = __ballot(blu == wm);
    int l = __builtin_ctzll(mk);                      // lowest lane = lowest n
    int idx = __builtin_amdgcn_readlane(t*16+li, l);
    if (lane==0) part[it&1][w] = ((unsigned long long)wm<<32) | (unsigned)(NPTS-1-idx);
    __syncthreads();
    const ulonglong2* pp = (const ulonglong2*)&part[it&1][0];
    ulonglong2 A = pp[0], B = pp[1];
    unsigned long long m = umax64(umax64(A.x,A.y), umax64(B.x,B.y));
    far = NPTS-1 - (int)(m & 0xffffffffu);
  }
}

// ---------------------------------------------------------------------------
// kNN v5: radix-histogram selection. v3's 32-round tournament cost ~1340
// instr/thread (VALUBusy 101%, 162 us); selection needs only ~450:
// 1) dv[16] dist-keys in regs (same exact math; key u32 order-preserving map)
// 2) LDS histogram over key>>20 (4096 bins, monotone)
// 3) 3-level serial prefix on t0 finds bin beta holding the 32nd smallest
// 4) append all keys with bin<=beta (~72) to cand[] via LDS atomic
// 5) exact rank of each candidate among candidates (unique u64 (dist,idx)
//    keys) -> rank<32 scatters. Set AND order == lax.top_k(-d) exactly.
// ---------------------------------------------------------------------------
__global__ __launch_bounds__(256) void knn_kernel(const void* __restrict__ pc1,
                                                  const int* __restrict__ fps_idx,
                                                  float* __restrict__ new_xyz,
                                                  int* __restrict__ knn_idx){
  __shared__ __align__(16) unsigned hist[4096];           // 16 KB
  __shared__ __align__(16) unsigned long long cand[512];  // 4 KB
  __shared__ unsigned part[256];
  __shared__ unsigned sup[16];
  __shared__ unsigned scal[2];                            // [0]=cnt, [1]=beta
  int blk = blockIdx.x;   // b*1024 + s
  int b = blk >> 10;
  int t = threadIdx.x;
  const bool f32 = detect_f32((const unsigned short*)pc1);
  const size_t base = (size_t)b*3*NPTS;
  int n0 = fps_idx[blk];
  float qx = ldin(pc1, base+n0, f32);
  float qy = ldin(pc1, base+NPTS+n0, f32);
  float qz = ldin(pc1, base+2*NPTS+n0, f32);
  if (t==0){
    new_xyz[(size_t)blk*3]=qx; new_xyz[(size_t)blk*3+1]=qy; new_xyz[(size_t)blk*3+2]=qz;
    scal[0]=0u;
  }
  // zero histogram (interleaved: conflict-free)
  #pragma unroll
  for (int j=0;j<16;j++) hist[j*256 + t] = 0u;
  float qn = __fadd_rn(__fadd_rn(__fmul_rn(qx,qx),__fmul_rn(qy,qy)),__fmul_rn(qz,qz));
  unsigned dv[16];
  #pragma unroll
  for (int k=0;k<16;k++){
    int n = t + 256*k;                               // coalesced global reads
    float x = ldin(pc1, base+n, f32);
    float y = ldin(pc1, base+NPTS+n, f32);
    float z = ldin(pc1, base+2*NPTS+n, f32);
    float pn = __fadd_rn(__fadd_rn(__fmul_rn(x,x),__fmul_rn(y,y)),__fmul_rn(z,z));
    float dt = __fadd_rn(__fadd_rn(__fmul_rn(qx,x),__fmul_rn(qy,y)),__fmul_rn(qz,z));
    float d  = __fsub_rn(__fadd_rn(qn,pn), __fmul_rn(2.f,dt));
    unsigned u = __float_as_uint(d);
    dv[k] = (u & 0x80000000u) ? ~u : (u | 0x80000000u);  // order-preserving map
  }
  __syncthreads();
  #pragma unroll
  for (int k=0;k<16;k++)
    atomicAdd(&hist[dv[k]>>20], 1u);                 // ds_add_u32, ~random bins
  __syncthreads();
  { // partial sums: thread t covers bins [t*16, t*16+16)
    unsigned s = 0;
    const uint4* hp = (const uint4*)&hist[t*16];
    #pragma unroll
    for (int j=0;j<4;j++){
      uint4 v = hp[j];
      s += v.x + v.y + v.z + v.w;
    }
    part[t] = s;
  }
  __syncthreads();
  if (t < 16){
    unsigned q = 0;
    #pragma unroll
    for (int j=0;j<16;j++) q += part[t*16 + j];
    sup[t] = q;
  }
  __syncthreads();
  if (t == 0){
    unsigned acc = 0; int sb = 0;
    for (; sb < 16; sb++){ unsigned v = sup[sb]; if (acc + v >= NK) break; acc += v; }
    int pt = sb*16;
    for (; pt < sb*16+16; pt++){ unsigned v = part[pt]; if (acc + v >= NK) break; acc += v; }
    int bn = pt*16;
    for (; bn < pt*16+16; bn++){ unsigned v = hist[bn]; if (acc + v >= NK) break; acc += v; }
    scal[1] = (unsigned)bn;
  }
  __syncthreads();
  unsigned beta = scal[1];
  #pragma unroll
  for (int k=0;k<16;k++){
    if ((dv[k]>>20) <= beta){
      unsigned pos = atomicAdd(&scal[0], 1u);
      if (pos < 512u)
        cand[pos] = ((unsigned long long)dv[k]<<32) | (unsigned)(t + 256*k);
    }
  }
  __syncthreads();
  int C = (int)scal[0]; if (C > 512) C = 512;
  for (int tt = t; tt < C; tt += 256){
    unsigned long long K = cand[tt];
    int rank = 0;
    for (int j = 0; j < C; j++) rank += (cand[j] < K) ? 1 : 0;   // broadcast reads
    if (rank < NK) knn_idx[(size_t)blk*NK + rank] = (int)(K & 0xffffffffu);
  }
}

// ---------------------------------------------------------------------------
// feats [B,128,N] (f32/bf16) -> G [B,N,136] fp16; block 0 also zeroes the six
// stat buffers (6144 f32) so no memset nodes are needed (ws is 0xAA-poisoned).
// ---------------------------------------------------------------------------
__global__ __launch_bounds__(256) void feat_transpose(const void* __restrict__ feats,
                                                      const void* __restrict__ pc1,
                                                      _Float16* __restrict__ G,
                                                      float* __restrict__ statz){
  __shared__ float tile[128][65];
  const bool f32 = detect_f32((const unsigned short*)pc1);
  int blk = blockIdx.x;             // b*64 + ntile
  int b = blk>>6, n0 = (blk&63)*64;
  int t = threadIdx.x;
  if (blk==0){
    for (int i=t;i<6144;i+=256) statz[i]=0.f;
  }
  #pragma unroll 4
  for (int i=0;i<32;i++){
    int idx = i*256 + t;
    int c = idx>>6, n = idx&63;
    tile[c][n] = ldin(feats, ((size_t)b*128 + c)*NPTS + n0 + n, f32);
  }
  __syncthreads();
  #pragma unroll 4
  for (int i=0;i<32;i++){
    int idx = i*256 + t;
    int n = idx>>7, c = idx&127;
    G[((size_t)b*NPTS + n0 + n)*136 + 3 + c] = (_Float16)tile[c][n];
  }
  if (t<64){
    size_t gb = ((size_t)b*NPTS + n0 + t)*136;
    G[gb]=(_Float16)0.f; G[gb+1]=(_Float16)0.f; G[gb+2]=(_Float16)0.f;
    #pragma unroll
    for (int c=131;c<136;c++) G[gb+c]=(_Float16)0.f;
  }
}

// ---------------------------------------------------------------------------
// MFMA conv (r13): LDS-routed coalesced epilogue, packed-f16 norm staging,
// float4 W staging for aligned layers. Biases cancel under InstanceNorm.
// ---------------------------------------------------------------------------
template<int LAYER>
__global__ __launch_bounds__(256) void conv_mfma(
    const void* __restrict__ pc1,
    const _Float16* __restrict__ G,
    const int* __restrict__ knn_idx,
    const float* __restrict__ new_xyz,
    const _Float16* __restrict__ Hin,
    const float* __restrict__ gp1,
    const float* __restrict__ gp2,
    const void* __restrict__ W,
    _Float16* __restrict__ Hout,
    float* __restrict__ gs1, float* __restrict__ gs2)
{
  constexpr int KC  = (LAYER==1)?131:128;
  constexpr int KCP = (LAYER==1)?160:128;
  constexpr int HSW = (LAYER==1)?168:136;
  __shared__ __align__(16) _Float16 hs[128][HSW];
  __shared__ __align__(16) _Float16 wt[128][40];
  __shared__ float red1[4][64], red2[4][64];
  __shared__ int   nidx[128];
  __shared__ float cxyz[4][3];
  __shared__ __align__(16) _Float16 smuh[128], srsh[128];
  int blk = blockIdx.x;
  int m0 = blk*128;
  int b  = m0 >> 15;
  int t  = threadIdx.x;
  const bool f32 = detect_f32((const unsigned short*)pc1);
  int w = t>>6, lane = t&63;
  int l16 = lane&15, q = lane>>4, q8 = q*8;
  int wr = (w&1)*64, wc = (w>>1)*64;

  if (LAYER==1){
    if (t<128) nidx[t] = knn_idx[m0+t];
    if (t<12)  cxyz[t/3][t%3] = new_xyz[(size_t)(m0>>5)*3 + t];
    __syncthreads();
    for (int u=t; u<128*17; u+=256){
      int p = u/17, qq = u - p*17;
      const f16x8* src = (const f16x8*)(G + ((size_t)b*NPTS + nidx[p])*136 + qq*8);
      *(f16x8*)&hs[p][qq*8] = *src;
    }
    for (int u=t; u<128*3; u+=256){
      int p = u/3, qq = u - p*3;
      uint4 z; z.x=z.y=z.z=z.w=0u;
      *(uint4*)&hs[p][136+qq*8] = z;
    }
    __syncthreads();
    if (t<128){
      int n = nidx[t];
      float cx = cxyz[t>>5][0], cy = cxyz[t>>5][1], cz = cxyz[t>>5][2];
      hs[t][0] = (_Float16)(ldin(pc1, ((size_t)b*3+0)*NPTS+n, f32) - cx);
      hs[t][1] = (_Float16)(ldin(pc1, ((size_t)b*3+1)*NPTS+n, f32) - cy);
      hs[t][2] = (_Float16)(ldin(pc1, ((size_t)b*3+2)*NPTS+n, f32) - cz);
    }
    __syncthreads();
  } else {
    if (t<128){
      const float inv = 1.0f/32768.0f;
      float m = gp1[b*128+t]*inv;
      smuh[t] = (_Float16)m;
      srsh[t] = (_Float16)rsqrtf(gp2[b*128+t]*inv - m*m + 1e-5f);
    }
    __syncthreads();
    int p = t & 127, hi = t>>7;
    const _Float16* src = Hin + (size_t)(m0+p)*128 + hi*64;
    f16x8 zero8 = {};
    #pragma unroll
    for (int j=0;j<8;j++){
      f16x8 v   = *(const f16x8*)(src + j*8);
      f16x8 mu8 = *(const f16x8*)&smuh[hi*64 + j*8];
      f16x8 rs8 = *(const f16x8*)&srsh[hi*64 + j*8];
      f16x8 o = (v - mu8) * rs8;                    // v_pk_*_f16
      o = __builtin_elementwise_max(o, zero8);      // relu
      *(f16x8*)&hs[p][hi*64 + j*8] = o;
    }
    __syncthreads();
  }

  f32x4 acc[4][4];
  #pragma unroll
  for (int i=0;i<4;i++)
    #pragma unroll
    for (int c=0;c<4;c++){ acc[i][c][0]=0.f; acc[i][c][1]=0.f; acc[i][c][2]=0.f; acc[i][c][3]=0.f; }

  for (int k0=0; k0<KCP; k0+=32){
    {
      int o = t>>1, half = t&1;
      f16x8 w0, w1;
      if (f32 && LAYER!=1){
        const float4* Wf = (const float4*)((const float*)W + (size_t)o*KC + k0 + half*16);
        float4 v0 = Wf[0], v1 = Wf[1], v2 = Wf[2], v3 = Wf[3];
        w0[0]=(_Float16)v0.x; w0[1]=(_Float16)v0.y; w0[2]=(_Float16)v0.z; w0[3]=(_Float16)v0.w;
        w0[4]=(_Float16)v1.x; w0[5]=(_Float16)v1.y; w0[6]=(_Float16)v1.z; w0[7]=(_Float16)v1.w;
        w1[0]=(_Float16)v2.x; w1[1]=(_Float16)v2.y; w1[2]=(_Float16)v2.z; w1[3]=(_Float16)v2.w;
        w1[4]=(_Float16)v3.x; w1[5]=(_Float16)v3.y; w1[6]=(_Float16)v3.z; w1[7]=(_Float16)v3.w;
      } else {
        #pragma unroll
        for (int jj=0;jj<8;jj++){
          int c0 = k0 + half*16 + jj, c1 = c0 + 8;
          w0[jj] = (_Float16)((c0<KC) ? ldin(W, (size_t)o*KC + c0, f32) : 0.f);
          w1[jj] = (_Float16)((c1<KC) ? ldin(W, (size_t)o*KC + c1, f32) : 0.f);
        }
      }
      *(f16x8*)&wt[o][half*16]     = w0;
      *(f16x8*)&wt[o][half*16 + 8] = w1;
    }
    __syncthreads();
    f16x8 av[4], bv[4];
    #pragma unroll
    for (int i=0;i<4;i++) av[i] = *(const f16x8*)&hs[wr + i*16 + l16][k0 + q8];
    #pragma unroll
    for (int c=0;c<4;c++) bv[c] = *(const f16x8*)&wt[wc + c*16 + l16][q8];
    #pragma unroll
    for (int i=0;i<4;i++)
      #pragma unroll
      for (int c=0;c<4;c++)
        acc[i][c] = __builtin_amdgcn_mfma_f32_16x16x32_f16(av[i], bv[c], acc[i][c], 0,0,0);
    __syncthreads();
  }

  // epilogue: stats from f32 acc (unchanged math) + C -> hs (f16) -> coalesced
  #pragma unroll
  for (int c=0;c<4;c++){
    int o = wc + c*16 + l16;
    float s1=0.f, s2=0.f;
    #pragma unroll
    for (int i=0;i<4;i++){
      int row = wr + i*16 + q*4;
      #pragma unroll
      for (int r=0;r<4;r++){
        float v = acc[i][c][r];
        hs[row + r][o] = (_Float16)v;
        s1 += v; s2 = fmaf(v,v,s2);
      }
    }
    s1 += __shfl_xor(s1, 16, 64); s1 += __shfl_xor(s1, 32, 64);
    s2 += __shfl_xor(s2, 16, 64); s2 += __shfl_xor(s2, 32, 64);
    if (q==0){ red1[w][c*16+l16] = s1; red2[w][c*16+l16] = s2; }
  }
  __syncthreads();
  // coalesced store: chunk fi = j*256+t covers flat half-range [fi*8, fi*8+8)
  _Float16* dst0 = Hout + (size_t)m0*128;
  #pragma unroll
  for (int j=0;j<8;j++){
    int fi = j*256 + t;
    int row = fi >> 4, col = (fi & 15)*8;
    *(f16x8*)(dst0 + (size_t)fi*8) = *(const f16x8*)&hs[row][col];
  }
  if (t<128){
    int lo = t & 63, g = (t>>6)*2;
    unsafeAtomicAdd(&gs1[b*128+t], red1[g][lo] + red1[g+1][lo]);
    unsafeAtomicAdd(&gs2[b*128+t], red2[g][lo] + red2[g+1][lo]);
  }
}

// ---------------------------------------------------------------------------
// Final: per (b,s): mu/rs from layer-3 sums, norm+relu, max over K, fc 128->3
// ---------------------------------------------------------------------------
__global__ __launch_bounds__(128) void final_kernel(
    const void* __restrict__ pc1,
    const _Float16* __restrict__ H,
    const float* __restrict__ gp1, const float* __restrict__ gp2,
    const void* __restrict__ fc_w, const void* __restrict__ fc_b,
    void* __restrict__ outv)
{
  int blk = blockIdx.x;       // b*1024+s
  int b = blk>>10, s = blk & 1023;
  int o = threadIdx.x;
  const bool f32 = detect_f32((const unsigned short*)pc1);
  int bo = b*128 + o;
  const float inv = 1.0f/32768.0f;
  float mu_ = gp1[bo]*inv;
  float rs_ = rsqrtf(gp2[bo]*inv - mu_*mu_ + 1e-5f);
  const _Float16* hp = H + (size_t)blk*NK*128 + o;
  float m = -1e30f;
  #pragma unroll 4
  for(int k=0;k<NK;k++){
    float v = ((float)hp[(size_t)k*128] - mu_)*rs_;
    m = fmaxf(m, v);
  }
  m = fmaxf(m, 0.f);
  __shared__ float mv[128];
  mv[o] = m;
  __syncthreads();
  if (o<3){
    float acc = ldin(fc_b, o, f32);
    for(int c=0;c<128;c++) acc = fmaf(ldin(fc_w, (size_t)o*128+c, f32), mv[c], acc);
    size_t oi = ((size_t)b*3 + o)*NS + s;
    if (f32) ((float*)outv)[oi] = acc;
    else     ((unsigned short*)outv)[oi] = f2bf(acc);
  }
}

// ---------------------------------------------------------------------------
extern "C" void kernel_launch(void* const* d_in, const int* in_sizes, int n_in,
                              void* d_out, int out_size, void* d_ws, size_t ws_size,
                              hipStream_t stream){
  const void* pc1   = d_in[0];
  const void* feats = d_in[1];
  const void* W1    = d_in[2];
  const void* W2    = d_in[4];
  const void* W3    = d_in[6];
  const void* fcw   = d_in[8];
  const void* fcb   = d_in[9];
  char* ws = (char*)d_ws;
  int*      fps  = (int*)     (ws + 0);          // 32768 B
  float*    nxyz = (float*)   (ws + 32768);      // 98304 B
  int*      knn  = (int*)     (ws + 131072);     // 1048576 B
  float*    st   = (float*)   (ws + 1179648);    // 6*1024*4 = 24576 B  [s1a s2a s1b s2b s1c s2c]
  _Float16* Ha   = (_Float16*)(ws + 1204224);    // 67108864 B
  _Float16* Hb   = (_Float16*)(ws + 68313088);   // 67108864 B (total 135421952)
  _Float16* G    = Hb;  // G (8.9 MB) aliases Hb: read only by conv1, Hb first written by conv2

  feat_transpose<<<NB*64, 256, 0, stream>>>(feats, pc1, G, st);
  fps_kernel<<<NB, 256, 0, stream>>>(pc1, fps);
  knn_kernel<<<NB*NS, 256, 0, stream>>>(pc1, fps, nxyz, knn);

  conv_mfma<1><<<NM/128, 256, 0, stream>>>(pc1, G, knn, nxyz,
      (const _Float16*)nullptr, (const float*)nullptr, (const float*)nullptr,
      W1, Ha, st, st+1024);
  conv_mfma<2><<<NM/128, 256, 0, stream>>>(pc1, G, knn, nxyz,
      Ha, st, st+1024, W2, Hb, st+2048, st+3072);
  conv_mfma<3><<<NM/128, 256, 0, stream>>>(pc1, G, knn, nxyz,
      Hb, st+2048, st+3072, W3, Ha, st+4096, st+5120);

  final_kernel<<<NB*NS, 128, 0, stream>>>(pc1, Ha, st+4096, st+5120, fcw, fcb, d_out);
}

// Round 15
// 1052.188 us; speedup vs baseline: 1.2498x; 1.0069x over previous
//
#include <hip/hip_runtime.h>
#include <hip/hip_fp16.h>

#define NB 8
#define NPTS 4096
#define NS 1024
#define NK 32
#define NM (NB*NS*NK)   // 262144 grouped points

typedef _Float16 f16x8 __attribute__((ext_vector_type(8)));
typedef float    f32x4 __attribute__((ext_vector_type(4)));
typedef float    f32x2 __attribute__((ext_vector_type(2)));

__device__ __forceinline__ float bf2f(unsigned short u){ return __uint_as_float(((unsigned)u)<<16); }
__device__ __forceinline__ unsigned short f2bf(float f){
  unsigned u = __float_as_uint(f);
  u = u + 0x7fffu + ((u>>16)&1u);   // RNE
  return (unsigned short)(u>>16);
}
__device__ __forceinline__ unsigned long long umax64(unsigned long long a, unsigned long long b){ return a>b?a:b; }

// ---- DPP wave64 reduce: row_shr 1/2/4/8 + row_bcast 15/31, result in lane 63.
#define DPP_STEP_MAX(x, ctrl, rm) { \
  unsigned _t = (unsigned)__builtin_amdgcn_update_dpp((int)(x), (int)(x), (ctrl), (rm), 0xf, false); \
  (x) = ((x) > _t) ? (x) : _t; }

__device__ __forceinline__ unsigned wave_max_u32(unsigned x){
  DPP_STEP_MAX(x, 0x111, 0xf);
  DPP_STEP_MAX(x, 0x112, 0xf);
  DPP_STEP_MAX(x, 0x114, 0xf);
  DPP_STEP_MAX(x, 0x118, 0xf);
  DPP_STEP_MAX(x, 0x142, 0xa);
  DPP_STEP_MAX(x, 0x143, 0xc);
  return (unsigned)__builtin_amdgcn_readlane((int)x, 63);
}

// Runtime dtype detection (block-uniform scalar branch): f32 data read as bf16
// halves decodes huge/denormal or exact-zero; true bf16 N(0,1) does not.
__device__ __forceinline__ bool detect_f32(const unsigned short* __restrict__ u){
  int huge_=0, zero_=0;
  #pragma unroll
  for (int i=0;i<64;i++){
    unsigned short w = u[i];
    if ((w & 0x7fffu) == 0) { zero_++; continue; }
    float a = fabsf(bf2f(w));
    if (a > 1e6f || a < 1e-6f) huge_++;
  }
  return (huge_ >= 8) || (zero_ >= 24);
}
__device__ __forceinline__ float ldin(const void* p, size_t i, bool f32){
  if (f32) return ((const float*)p)[i];
  else     return bf2f(((const unsigned short*)p)[i]);
}

// ---------------------------------------------------------------------------
// Fused FPS + feat_transpose. Blocks 0-7: FPS (round-10 verbatim, 531 us,
// latency-bound, VALUBusy 1.7%). Blocks 8-519: feats [B,128,N] -> G [B,N,136]
// fp16 transpose + stat zeroing — runs on the 248 CUs fps leaves idle,
// hiding its ~25 us entirely. LDS overlaid via char array (max of the two
// layouts, 65.6 KB -> fps keeps its 1-2 blocks/CU register generosity).
// ---------------------------------------------------------------------------
__global__ __launch_bounds__(256) void fps_fused(const void* __restrict__ pc1,
                                                 const void* __restrict__ feats,
                                                 int* __restrict__ fps_out,
                                                 _Float16* __restrict__ G,
                                                 float* __restrict__ statz){
  __shared__ __align__(16) char smem[65600];
  int t = threadIdx.x;
  const bool f32 = detect_f32((const unsigned short*)pc1);
  if (blockIdx.x < 8){
    float4* cp4 = (float4*)smem;
    unsigned long long (*part)[4] = (unsigned long long (*)[4])(smem + 65536);
    int b = blockIdx.x;
    const size_t base = (size_t)b*3*NPTS;
    for (int i=t;i<NPTS;i+=256){
      float4 v;
      v.x = ldin(pc1, base+i, f32);
      v.y = ldin(pc1, base+NPTS+i, f32);
      v.z = ldin(pc1, base+2*NPTS+i, f32);
      v.w = 0.f;
      cp4[i] = v;
    }
    __syncthreads();
    f32x2 px[8],py[8],pz[8],dist[8];
    #pragma unroll
    for (int j=0;j<8;j++){
      float4 a = cp4[t*16+2*j], c = cp4[t*16+2*j+1];
      px[j] = f32x2{a.x, c.x};
      py[j] = f32x2{a.y, c.y};
      pz[j] = f32x2{a.z, c.z};
      dist[j] = f32x2{1e10f, 1e10f};
    }
    int far = 0;
    int w = t>>6, lane = t&63;
    for (int it=0; it<NS; it++){
      if (t==0) fps_out[b*NS+it] = far;
      float4 cc = cp4[far];
      f32x2 vcx = f32x2{cc.x,cc.x}, vcy = f32x2{cc.y,cc.y}, vcz = f32x2{cc.z,cc.z};
      {
        #pragma clang fp contract(off)
        #pragma unroll
        for (int j=0;j<8;j++){
          f32x2 dx = px[j]-vcx, dy = py[j]-vcy, dz = pz[j]-vcz;
          f32x2 d  = (dx*dx + dy*dy) + dz*dz;     // exact RN order: ((x2+y2)+z2)
          dist[j]  = __builtin_elementwise_min(dist[j], d);
        }
      }
      float d_[16];
      #pragma unroll
      for (int j=0;j<8;j++){ d_[2*j]=dist[j][0]; d_[2*j+1]=dist[j][1]; }
      float a0 = fmaxf(fmaxf(d_[0],d_[1]),d_[2]);      // -> v_max3_f32
      float a1 = fmaxf(fmaxf(d_[3],d_[4]),d_[5]);
      float a2 = fmaxf(fmaxf(d_[6],d_[7]),d_[8]);
      float a3 = fmaxf(fmaxf(d_[9],d_[10]),d_[11]);
      float a4 = fmaxf(fmaxf(d_[12],d_[13]),d_[14]);
      float b0 = fmaxf(fmaxf(a0,a1),a2);
      float b1 = fmaxf(fmaxf(a3,a4),d_[15]);
      float bl = fmaxf(b0,b1);
      int li = 0;
      #pragma unroll
      for (int i=15;i>=0;i--) if (d_[i]==bl) li = i;   // descending: final = lowest i
      unsigned blu = __float_as_uint(bl);               // dist>=0: bits monotone
      unsigned wm = wave_max_u32(blu);
      unsigned long long mk = __ballot(blu == wm);
      int l = __builtin_ctzll(mk);                      // lowest lane = lowest n
      int idx = __builtin_amdgcn_readlane(t*16+li, l);
      if (lane==0) part[it&1][w] = ((unsigned long long)wm<<32) | (unsigned)(NPTS-1-idx);
      __syncthreads();
      const ulonglong2* pp = (const ulonglong2*)&part[it&1][0];
      ulonglong2 A = pp[0], B = pp[1];
      unsigned long long m = umax64(umax64(A.x,A.y), umax64(B.x,B.y));
      far = NPTS-1 - (int)(m & 0xffffffffu);
    }
  } else {
    float (*tile)[65] = (float (*)[65])smem;
    int blk = blockIdx.x - 8;          // b*64 + ntile
    int b = blk>>6, n0 = (blk&63)*64;
    if (blk==0){
      for (int i=t;i<6144;i+=256) statz[i]=0.f;
    }
    #pragma unroll 4
    for (int i=0;i<32;i++){
      int idx = i*256 + t;
      int c = idx>>6, n = idx&63;
      tile[c][n] = ldin(feats, ((size_t)b*128 + c)*NPTS + n0 + n, f32);
    }
    __syncthreads();
    #pragma unroll 4
    for (int i=0;i<32;i++){
      int idx = i*256 + t;
      int n = idx>>7, c = idx&127;
      G[((size_t)b*NPTS + n0 + n)*136 + 3 + c] = (_Float16)tile[c][n];
    }
    if (t<64){
      size_t gb = ((size_t)b*NPTS + n0 + t)*136;
      G[gb]=(_Float16)0.f; G[gb+1]=(_Float16)0.f; G[gb+2]=(_Float16)0.f;
      #pragma unroll
      for (int c=131;c<136;c++) G[gb+c]=(_Float16)0.f;
    }
  }
}

// ---------------------------------------------------------------------------
// kNN v5 (r14, kept): radix-histogram selection, ~129 us.
// ---------------------------------------------------------------------------
__global__ __launch_bounds__(256) void knn_kernel(const void* __restrict__ pc1,
                                                  const int* __restrict__ fps_idx,
                                                  float* __restrict__ new_xyz,
                                                  int* __restrict__ knn_idx){
  __shared__ __align__(16) unsigned hist[4096];           // 16 KB
  __shared__ __align__(16) unsigned long long cand[512];  // 4 KB
  __shared__ unsigned part[256];
  __shared__ unsigned sup[16];
  __shared__ unsigned scal[2];                            // [0]=cnt, [1]=beta
  int blk = blockIdx.x;   // b*1024 + s
  int b = blk >> 10;
  int t = threadIdx.x;
  const bool f32 = detect_f32((const unsigned short*)pc1);
  const size_t base = (size_t)b*3*NPTS;
  int n0 = fps_idx[blk];
  float qx = ldin(pc1, base+n0, f32);
  float qy = ldin(pc1, base+NPTS+n0, f32);
  float qz = ldin(pc1, base+2*NPTS+n0, f32);
  if (t==0){
    new_xyz[(size_t)blk*3]=qx; new_xyz[(size_t)blk*3+1]=qy; new_xyz[(size_t)blk*3+2]=qz;
    scal[0]=0u;
  }
  #pragma unroll
  for (int j=0;j<16;j++) hist[j*256 + t] = 0u;
  float qn = __fadd_rn(__fadd_rn(__fmul_rn(qx,qx),__fmul_rn(qy,qy)),__fmul_rn(qz,qz));
  unsigned dv[16];
  #pragma unroll
  for (int k=0;k<16;k++){
    int n = t + 256*k;                               // coalesced global reads
    float x = ldin(pc1, base+n, f32);
    float y = ldin(pc1, base+NPTS+n, f32);
    float z = ldin(pc1, base+2*NPTS+n, f32);
    float pn = __fadd_rn(__fadd_rn(__fmul_rn(x,x),__fmul_rn(y,y)),__fmul_rn(z,z));
    float dt = __fadd_rn(__fadd_rn(__fmul_rn(qx,x),__fmul_rn(qy,y)),__fmul_rn(qz,z));
    float d  = __fsub_rn(__fadd_rn(qn,pn), __fmul_rn(2.f,dt));
    unsigned u = __float_as_uint(d);
    dv[k] = (u & 0x80000000u) ? ~u : (u | 0x80000000u);  // order-preserving map
  }
  __syncthreads();
  #pragma unroll
  for (int k=0;k<16;k++)
    atomicAdd(&hist[dv[k]>>20], 1u);
  __syncthreads();
  {
    unsigned s = 0;
    const uint4* hp = (const uint4*)&hist[t*16];
    #pragma unroll
    for (int j=0;j<4;j++){
      uint4 v = hp[j];
      s += v.x + v.y + v.z + v.w;
    }
    part[t] = s;
  }
  __syncthreads();
  if (t < 16){
    unsigned q = 0;
    #pragma unroll
    for (int j=0;j<16;j++) q += part[t*16 + j];
    sup[t] = q;
  }
  __syncthreads();
  if (t == 0){
    unsigned acc = 0; int sb = 0;
    for (; sb < 16; sb++){ unsigned v = sup[sb]; if (acc + v >= NK) break; acc += v; }
    int pt = sb*16;
    for (; pt < sb*16+16; pt++){ unsigned v = part[pt]; if (acc + v >= NK) break; acc += v; }
    int bn = pt*16;
    for (; bn < pt*16+16; bn++){ unsigned v = hist[bn]; if (acc + v >= NK) break; acc += v; }
    scal[1] = (unsigned)bn;
  }
  __syncthreads();
  unsigned beta = scal[1];
  #pragma unroll
  for (int k=0;k<16;k++){
    if ((dv[k]>>20) <= beta){
      unsigned pos = atomicAdd(&scal[0], 1u);
      if (pos < 512u)
        cand[pos] = ((unsigned long long)dv[k]<<32) | (unsigned)(t + 256*k);
    }
  }
  __syncthreads();
  int C = (int)scal[0]; if (C > 512) C = 512;
  for (int tt = t; tt < C; tt += 256){
    unsigned long long K = cand[tt];
    int rank = 0;
    for (int j = 0; j < C; j++) rank += (cand[j] < K) ? 1 : 0;   // broadcast reads
    if (rank < NK) knn_idx[(size_t)blk*NK + rank] = (int)(K & 0xffffffffu);
  }
}

// ---------------------------------------------------------------------------
// MFMA conv. LAYER 1: r13 structure (wt LDS staging + barriers; K=131 ragged).
// LAYER 2/3: barrier-free K-loop — B-fragments loaded DIRECT from global W
// (rows 512 B / 256 B aligned; L2-hot 64 KB) with identical per-element RNE
// f16 cvt; wt[] and its 8 barriers/block deleted so the ds_read/MFMA stream
// pipelines. amdgpu_waves_per_eu(1,3) pins the register budget (r9-verified
// binding) so the smaller LDS can't re-trigger the r7 occupancy/spill cliff.
// ---------------------------------------------------------------------------
template<int LAYER>
__global__ __launch_bounds__(256)
__attribute__((amdgpu_waves_per_eu(1,3)))
void conv_mfma(
    const void* __restrict__ pc1,
    const _Float16* __restrict__ G,
    const int* __restrict__ knn_idx,
    const float* __restrict__ new_xyz,
    const _Float16* __restrict__ Hin,
    const float* __restrict__ gp1,
    const float* __restrict__ gp2,
    const void* __restrict__ W,
    _Float16* __restrict__ Hout,
    float* __restrict__ gs1, float* __restrict__ gs2)
{
  constexpr int KC  = (LAYER==1)?131:128;
  constexpr int KCP = (LAYER==1)?160:128;
  constexpr int HSW = (LAYER==1)?168:136;
  __shared__ __align__(16) _Float16 hs[128][HSW];
  __shared__ __align__(16) _Float16 wt[(LAYER==1)?128:1][40];
  __shared__ float red1[4][64], red2[4][64];
  __shared__ int   nidx[128];
  __shared__ float cxyz[4][3];
  __shared__ __align__(16) _Float16 smuh[128], srsh[128];
  int blk = blockIdx.x;
  int m0 = blk*128;
  int b  = m0 >> 15;
  int t  = threadIdx.x;
  const bool f32 = detect_f32((const unsigned short*)pc1);
  int w = t>>6, lane = t&63;
  int l16 = lane&15, q = lane>>4, q8 = q*8;
  int wr = (w&1)*64, wc = (w>>1)*64;

  if (LAYER==1){
    if (t<128) nidx[t] = knn_idx[m0+t];
    if (t<12)  cxyz[t/3][t%3] = new_xyz[(size_t)(m0>>5)*3 + t];
    __syncthreads();
    for (int u=t; u<128*17; u+=256){
      int p = u/17, qq = u - p*17;
      const f16x8* src = (const f16x8*)(G + ((size_t)b*NPTS + nidx[p])*136 + qq*8);
      *(f16x8*)&hs[p][qq*8] = *src;
    }
    for (int u=t; u<128*3; u+=256){
      int p = u/3, qq = u - p*3;
      uint4 z; z.x=z.y=z.z=z.w=0u;
      *(uint4*)&hs[p][136+qq*8] = z;
    }
    __syncthreads();
    if (t<128){
      int n = nidx[t];
      float cx = cxyz[t>>5][0], cy = cxyz[t>>5][1], cz = cxyz[t>>5][2];
      hs[t][0] = (_Float16)(ldin(pc1, ((size_t)b*3+0)*NPTS+n, f32) - cx);
      hs[t][1] = (_Float16)(ldin(pc1, ((size_t)b*3+1)*NPTS+n, f32) - cy);
      hs[t][2] = (_Float16)(ldin(pc1, ((size_t)b*3+2)*NPTS+n, f32) - cz);
    }
    __syncthreads();
  } else {
    if (t<128){
      const float inv = 1.0f/32768.0f;
      float m = gp1[b*128+t]*inv;
      smuh[t] = (_Float16)m;
      srsh[t] = (_Float16)rsqrtf(gp2[b*128+t]*inv - m*m + 1e-5f);
    }
    __syncthreads();
    int p = t & 127, hi = t>>7;
    const _Float16* src = Hin + (size_t)(m0+p)*128 + hi*64;
    f16x8 zero8 = {};
    #pragma unroll
    for (int j=0;j<8;j++){
      f16x8 v   = *(const f16x8*)(src + j*8);
      f16x8 mu8 = *(const f16x8*)&smuh[hi*64 + j*8];
      f16x8 rs8 = *(const f16x8*)&srsh[hi*64 + j*8];
      f16x8 o = (v - mu8) * rs8;                    // v_pk_*_f16
      o = __builtin_elementwise_max(o, zero8);      // relu
      *(f16x8*)&hs[p][hi*64 + j*8] = o;
    }
    __syncthreads();
  }

  f32x4 acc[4][4];
  #pragma unroll
  for (int i=0;i<4;i++)
    #pragma unroll
    for (int c=0;c<4;c++){ acc[i][c][0]=0.f; acc[i][c][1]=0.f; acc[i][c][2]=0.f; acc[i][c][3]=0.f; }

  if (LAYER==1){
    for (int k0=0; k0<KCP; k0+=32){
      {
        int o = t>>1, half = t&1;
        f16x8 w0, w1;
        #pragma unroll
        for (int jj=0;jj<8;jj++){
          int c0 = k0 + half*16 + jj, c1 = c0 + 8;
          w0[jj] = (_Float16)((c0<KC) ? ldin(W, (size_t)o*KC + c0, f32) : 0.f);
          w1[jj] = (_Float16)((c1<KC) ? ldin(W, (size_t)o*KC + c1, f32) : 0.f);
        }
        *(f16x8*)&wt[o][half*16]     = w0;
        *(f16x8*)&wt[o][half*16 + 8] = w1;
      }
      __syncthreads();
      f16x8 av[4], bv[4];
      #pragma unroll
      for (int i=0;i<4;i++) av[i] = *(const f16x8*)&hs[wr + i*16 + l16][k0 + q8];
      #pragma unroll
      for (int c=0;c<4;c++) bv[c] = *(const f16x8*)&wt[wc + c*16 + l16][q8];
      #pragma unroll
      for (int i=0;i<4;i++)
        #pragma unroll
        for (int c=0;c<4;c++)
          acc[i][c] = __builtin_amdgcn_mfma_f32_16x16x32_f16(av[i], bv[c], acc[i][c], 0,0,0);
      __syncthreads();
    }
  } else {
    // barrier-free K-loop: B-frags direct from global (L2-hot), A from LDS
    #pragma unroll
    for (int k0=0; k0<128; k0+=32){
      f16x8 av[4], bv[4];
      #pragma unroll
      for (int i=0;i<4;i++) av[i] = *(const f16x8*)&hs[wr + i*16 + l16][k0 + q8];
      #pragma unroll
      for (int c=0;c<4;c++){
        int row = wc + c*16 + l16;
        if (f32){
          const f32x4* Wr = (const f32x4*)((const float*)W + (size_t)row*128 + k0 + q8);
          f32x4 v0 = Wr[0], v1 = Wr[1];
          f16x8 bb;
          bb[0]=(_Float16)v0[0]; bb[1]=(_Float16)v0[1]; bb[2]=(_Float16)v0[2]; bb[3]=(_Float16)v0[3];
          bb[4]=(_Float16)v1[0]; bb[5]=(_Float16)v1[1]; bb[6]=(_Float16)v1[2]; bb[7]=(_Float16)v1[3];
          bv[c] = bb;
        } else {
          const ushort4* Wr = (const ushort4*)((const unsigned short*)W + (size_t)row*128 + k0 + q8);
          ushort4 u0 = Wr[0], u1 = Wr[1];
          f16x8 bb;
          bb[0]=(_Float16)bf2f(u0.x); bb[1]=(_Float16)bf2f(u0.y); bb[2]=(_Float16)bf2f(u0.z); bb[3]=(_Float16)bf2f(u0.w);
          bb[4]=(_Float16)bf2f(u1.x); bb[5]=(_Float16)bf2f(u1.y); bb[6]=(_Float16)bf2f(u1.z); bb[7]=(_Float16)bf2f(u1.w);
          bv[c] = bb;
        }
      }
      #pragma unroll
      for (int i=0;i<4;i++)
        #pragma unroll
        for (int c=0;c<4;c++)
          acc[i][c] = __builtin_amdgcn_mfma_f32_16x16x32_f16(av[i], bv[c], acc[i][c], 0,0,0);
    }
    __syncthreads();   // all waves done reading hs before epilogue overwrites
  }

  // epilogue: stats from f32 acc + C -> hs (f16) -> coalesced global stores
  #pragma unroll
  for (int c=0;c<4;c++){
    int o = wc + c*16 + l16;
    float s1=0.f, s2=0.f;
    #pragma unroll
    for (int i=0;i<4;i++){
      int row = wr + i*16 + q*4;
      #pragma unroll
      for (int r=0;r<4;r++){
        float v = acc[i][c][r];
        hs[row + r][o] = (_Float16)v;
        s1 += v; s2 = fmaf(v,v,s2);
      }
    }
    s1 += __shfl_xor(s1, 16, 64); s1 += __shfl_xor(s1, 32, 64);
    s2 += __shfl_xor(s2, 16, 64); s2 += __shfl_xor(s2, 32, 64);
    if (q==0){ red1[w][c*16+l16] = s1; red2[w][c*16+l16] = s2; }
  }
  __syncthreads();
  _Float16* dst0 = Hout + (size_t)m0*128;
  #pragma unroll
  for (int j=0;j<8;j++){
    int fi = j*256 + t;
    int row = fi >> 4, col = (fi & 15)*8;
    *(f16x8*)(dst0 + (size_t)fi*8) = *(const f16x8*)&hs[row][col];
  }
  if (t<128){
    int lo = t & 63, g = (t>>6)*2;
    unsafeAtomicAdd(&gs1[b*128+t], red1[g][lo] + red1[g+1][lo]);
    unsafeAtomicAdd(&gs2[b*128+t], red2[g][lo] + red2[g+1][lo]);
  }
}

// ---------------------------------------------------------------------------
// Final: LDS-staged coalesced loads (was 32 x 2B strided global reads/thread
// touching 64 cache lines per instr), then per-channel max + fc 128->3.
// ---------------------------------------------------------------------------
__global__ __launch_bounds__(128) void final_kernel(
    const void* __restrict__ pc1,
    const _Float16* __restrict__ H,
    const float* __restrict__ gp1, const float* __restrict__ gp2,
    const void* __restrict__ fc_w, const void* __restrict__ fc_b,
    void* __restrict__ outv)
{
  __shared__ __align__(16) _Float16 tile[32][136];
  __shared__ float mv[128];
  int blk = blockIdx.x;       // b*1024+s
  int b = blk>>10, s = blk & 1023;
  int o = threadIdx.x;
  const bool f32 = detect_f32((const unsigned short*)pc1);
  const _Float16* src = H + (size_t)blk*NK*128;
  #pragma unroll
  for (int j=0;j<4;j++){
    int fi = j*128 + o;                      // 512 f16x8 chunks, coalesced
    int row = fi >> 4, col = (fi & 15)*8;
    *(f16x8*)&tile[row][col] = *(const f16x8*)(src + (size_t)fi*8);
  }
  __syncthreads();
  int bo = b*128 + o;
  const float inv = 1.0f/32768.0f;
  float mu_ = gp1[bo]*inv;
  float rs_ = rsqrtf(gp2[bo]*inv - mu_*mu_ + 1e-5f);
  float m = -1e30f;
  #pragma unroll 4
  for (int k=0;k<NK;k++){
    float v = ((float)tile[k][o] - mu_)*rs_;
    m = fmaxf(m, v);
  }
  m = fmaxf(m, 0.f);   // max_k relu == relu(max_k)
  mv[o] = m;
  __syncthreads();
  if (o<3){
    float acc = ldin(fc_b, o, f32);
    for(int c=0;c<128;c++) acc = fmaf(ldin(fc_w, (size_t)o*128+c, f32), mv[c], acc);
    size_t oi = ((size_t)b*3 + o)*NS + s;
    if (f32) ((float*)outv)[oi] = acc;
    else     ((unsigned short*)outv)[oi] = f2bf(acc);
  }
}

// ---------------------------------------------------------------------------
extern "C" void kernel_launch(void* const* d_in, const int* in_sizes, int n_in,
                              void* d_out, int out_size, void* d_ws, size_t ws_size,
                              hipStream_t stream){
  const void* pc1   = d_in[0];
  const void* feats = d_in[1];
  const void* W1    = d_in[2];
  const void* W2    = d_in[4];
  const void* W3    = d_in[6];
  const void* fcw   = d_in[8];
  const void* fcb   = d_in[9];
  char* ws = (char*)d_ws;
  int*      fps  = (int*)     (ws + 0);          // 32768 B
  float*    nxyz = (float*)   (ws + 32768);      // 98304 B
  int*      knn  = (int*)     (ws + 131072);     // 1048576 B
  float*    st   = (float*)   (ws + 1179648);    // 6*1024*4 = 24576 B  [s1a s2a s1b s2b s1c s2c]
  _Float16* Ha   = (_Float16*)(ws + 1204224);    // 67108864 B
  _Float16* Hb   = (_Float16*)(ws + 68313088);   // 67108864 B (total 135421952)
  _Float16* G    = Hb;  // G (8.9 MB) aliases Hb: read only by conv1, Hb first written by conv2

  fps_fused<<<8 + NB*64, 256, 0, stream>>>(pc1, feats, fps, G, st);
  knn_kernel<<<NB*NS, 256, 0, stream>>>(pc1, fps, nxyz, knn);

  conv_mfma<1><<<NM/128, 256, 0, stream>>>(pc1, G, knn, nxyz,
      (const _Float16*)nullptr, (const float*)nullptr, (const float*)nullptr,
      W1, Ha, st, st+1024);
  conv_mfma<2><<<NM/128, 256, 0, stream>>>(pc1, G, knn, nxyz,
      Ha, st, st+1024, W2, Hb, st+2048, st+3072);
  conv_mfma<3><<<NM/128, 256, 0, stream>>>(pc1, G, knn, nxyz,
      Hb, st+2048, st+3072, W3, Ha, st+4096, st+5120);

  final_kernel<<<NB*NS, 128, 0, stream>>>(pc1, Ha, st+4096, st+5120, fcw, fcb, d_out);
}